// Round 7
// baseline (704.039 us; speedup 1.0000x reference)
//
#include <hip/hip_runtime.h>

#define HF 128  // feature width (F == H == 128)
#define NXCD 8
#define TILE 128      // cols per tile in hist/place
#define STAGE 16384   // staging entries per tile (mean ~4096; +68 sigma headroom)

__device__ __forceinline__ unsigned short f2bf(float f) {
    unsigned u = __float_as_uint(f);
    unsigned rounding = 0x7FFF + ((u >> 16) & 1);  // round-to-nearest-even
    return (unsigned short)((u + rounding) >> 16);
}

// ---------- phase A: bucket edges by col-range, packed 4B entries ----------
// entry = (c - g*step) << 17 | r   (step=6250 < 8192 -> 13 bits; r < 131072)
// Block-local two-phase append -> ~1KB contiguous chunks per bucket (full lines).
__global__ __launch_bounds__(256) void bucket_edges(const int* __restrict__ row,
                                                    const int* __restrict__ col,
                                                    unsigned* __restrict__ buckets,
                                                    int* __restrict__ cursor,
                                                    int E, int step, unsigned magic,
                                                    int cap) {
    __shared__ int lhist[NXCD], lbase[NXCD], lofs[NXCD];
    int t = threadIdx.x;
    if (t < NXCD) { lhist[t] = 0; lofs[t] = 0; }
    __syncthreads();
    int e0 = blockIdx.x * 2048 + t * 8;
    int cc[8], rr[8], pg[8];
    unsigned pk[8];
    if (e0 + 8 <= E) {
        int4 c0 = *reinterpret_cast<const int4*>(col + e0);
        int4 c1 = *reinterpret_cast<const int4*>(col + e0 + 4);
        int4 r0 = *reinterpret_cast<const int4*>(row + e0);
        int4 r1 = *reinterpret_cast<const int4*>(row + e0 + 4);
        cc[0]=c0.x; cc[1]=c0.y; cc[2]=c0.z; cc[3]=c0.w;
        cc[4]=c1.x; cc[5]=c1.y; cc[6]=c1.z; cc[7]=c1.w;
        rr[0]=r0.x; rr[1]=r0.y; rr[2]=r0.z; rr[3]=r0.w;
        rr[4]=r1.x; rr[5]=r1.y; rr[6]=r1.z; rr[7]=r1.w;
    } else {
        #pragma unroll
        for (int i = 0; i < 8; ++i) {
            int e = e0 + i;
            cc[i] = (e < E) ? col[e] : -1;
            rr[i] = (e < E) ? row[e] : 0;
        }
    }
    #pragma unroll
    for (int i = 0; i < 8; ++i) {
        if (cc[i] >= 0) {
            int g = (int)(((unsigned long long)(unsigned)cc[i] * magic) >> 32);
            pg[i] = g;
            pk[i] = ((unsigned)(cc[i] - g * step) << 17) | (unsigned)rr[i];
            atomicAdd(&lhist[g], 1);
        } else {
            pg[i] = -1;
        }
    }
    __syncthreads();
    if (t < NXCD) lbase[t] = lhist[t] ? atomicAdd(&cursor[t], lhist[t]) : 0;
    __syncthreads();
    #pragma unroll
    for (int i = 0; i < 8; ++i) {
        if (pg[i] >= 0) {
            int pos = lbase[pg[i]] + atomicAdd(&lofs[pg[i]], 1);
            buckets[(size_t)pg[i] * cap + pos] = pk[i];
        }
    }
}

// ---------- phase B: per-tile degree histogram (no global atomics) ----------
// block (g = blockIdx&7, sub = blockIdx>>3) owns cols [g*step + sub*TILE, +TILE);
// streams its XCD-local coarse bucket, LDS-counts its cols, writes cnt densely.
__global__ __launch_bounds__(256) void tile_hist(const unsigned* __restrict__ buckets,
                                                 const int* __restrict__ cursor,
                                                 int* __restrict__ cnt,
                                                 int step, int cap) {
    int g = blockIdx.x & (NXCD - 1);
    int sub = blockIdx.x >> 3;
    int lo = sub * TILE;
    int hi = min(lo + TILE, step);
    __shared__ int h[TILE];
    int t = threadIdx.x;
    if (t < TILE) h[t] = 0;
    __syncthreads();
    int sz = cursor[g];
    const unsigned* bk = buckets + (size_t)g * cap;
    for (int i = t; i < sz; i += 256) {
        int lc = (int)(bk[i] >> 17);
        if (lc >= lo && lc < hi) atomicAdd(&h[lc - lo], 1);
    }
    __syncthreads();
    if (t < hi - lo) cnt[g * step + lo + t] = h[t];
}

// ---------- scan pass1 + dinv fused ----------
__global__ __launch_bounds__(256) void scan_pass1(const int* __restrict__ cnt,
                                                  int* __restrict__ rowptr,
                                                  int* __restrict__ blocksum,
                                                  float* __restrict__ dinv, int N) {
    __shared__ int s[256];
    int t = threadIdx.x;
    int i = blockIdx.x * 256 + t;
    int v = (i < N) ? cnt[i] : 0;
    if (i < N) dinv[i] = rsqrtf((float)v + 1.0f);
    s[t] = v;
    __syncthreads();
    for (int o = 1; o < 256; o <<= 1) {
        int tv = (t >= o) ? s[t - o] : 0;
        __syncthreads();
        s[t] += tv;
        __syncthreads();
    }
    if (i < N) rowptr[i] = s[t] - v;  // block-local exclusive
    if (t == 255) blocksum[blockIdx.x] = s[255];
}

// fused pass2+3: each block reduces blocksum[0..blockIdx) itself (nb <= 256)
__global__ __launch_bounds__(256) void scan_pass23(int* __restrict__ rowptr,
                                                   const int* __restrict__ blocksum,
                                                   int N, int E, int nb) {
    __shared__ int s[256];
    int t = threadIdx.x;
    s[t] = (t < nb && t < blockIdx.x) ? blocksum[t] : 0;
    __syncthreads();
    for (int o = 128; o > 0; o >>= 1) {
        if (t < o) s[t] += s[t + o];
        __syncthreads();
    }
    int base = s[0];
    int i = blockIdx.x * 256 + t;
    if (i < N) rowptr[i] += base;
    if (blockIdx.x == 0 && t == 0) rowptr[N] = E;
}

// ---------- phase D: per-tile counting-sort place via LDS staging ----------
// Cursors derived from rowptr (no recount). Entries placed in LDS, then the
// whole tile segment is copied to srow contiguously -> full-line writes only.
__global__ __launch_bounds__(256) void tile_place(const unsigned* __restrict__ buckets,
                                                  const int* __restrict__ cursor,
                                                  const int* __restrict__ rowptr,
                                                  int* __restrict__ srow,
                                                  int step, int cap) {
    int g = blockIdx.x & (NXCD - 1);
    int sub = blockIdx.x >> 3;
    int lo = sub * TILE;
    int hi = min(lo + TILE, step);
    int clo = g * step;
    __shared__ int cur[TILE];
    __shared__ int stage[STAGE];
    int t = threadIdx.x;
    int base = rowptr[clo + lo];
    int tot = rowptr[clo + hi] - base;
    if (t < hi - lo) cur[t] = rowptr[clo + lo + t] - base;
    __syncthreads();
    int sz = cursor[g];
    const unsigned* bk = buckets + (size_t)g * cap;
    for (int i = t; i < sz; i += 256) {
        unsigned p = bk[i];
        int lc = (int)(p >> 17);
        if (lc >= lo && lc < hi) {
            int pos = atomicAdd(&cur[lc - lo], 1);
            if (pos < STAGE) stage[pos] = (int)(p & 0x1FFFFu);
        }
    }
    __syncthreads();
    if (tot > STAGE) tot = STAGE;  // statistically impossible; guards corruption
    for (int i = t; i < tot; i += 256) srow[base + i] = stage[i];
}

// ---------- GEMM: Y[N,128](bf16) = rowscale[r] * (BNReLU?(X[N,128]) @ W[128,128]) ----------
__global__ __launch_bounds__(128) void gemm128(const float* __restrict__ X,
                                               const float* __restrict__ W,
                                               unsigned short* __restrict__ Y,
                                               const float* __restrict__ scale,
                                               const float* __restrict__ shift,
                                               const float* __restrict__ rowscale,
                                               int N, int applyBN) {
    __shared__ float xs[16][HF];
    int t = threadIdx.x;
    int row0 = blockIdx.x * 16;
    float sc = applyBN ? scale[t] : 1.0f;
    float sh = applyBN ? shift[t] : 0.0f;
    for (int r = 0; r < 16; ++r) {
        int rr = row0 + r;
        float v = (rr < N) ? X[(size_t)rr * HF + t] : 0.0f;
        if (applyBN) v = fmaxf(v * sc + sh, 0.0f);
        xs[r][t] = v;
    }
    __syncthreads();
    for (int r0 = 0; r0 < 16; r0 += 4) {
        float a0 = 0.f, a1 = 0.f, a2 = 0.f, a3 = 0.f;
        #pragma unroll 8
        for (int f = 0; f < HF; ++f) {
            float w = W[f * HF + t];
            a0 += xs[r0 + 0][f] * w;
            a1 += xs[r0 + 1][f] * w;
            a2 += xs[r0 + 2][f] * w;
            a3 += xs[r0 + 3][f] * w;
        }
        int rr = row0 + r0;
        if (rr + 0 < N) Y[(size_t)(rr + 0) * HF + t] = f2bf(a0 * rowscale[rr + 0]);
        if (rr + 1 < N) Y[(size_t)(rr + 1) * HF + t] = f2bf(a1 * rowscale[rr + 1]);
        if (rr + 2 < N) Y[(size_t)(rr + 2) * HF + t] = f2bf(a2 * rowscale[rr + 2]);
        if (rr + 3 < N) Y[(size_t)(rr + 3) * HF + t] = f2bf(a3 * rowscale[rr + 3]);
    }
}

// ---------- gather-side conv on pre-scaled bf16 XWs ----------
__global__ __launch_bounds__(256) void gather_conv(const int* __restrict__ rowptr,
                                                   const int* __restrict__ srow,
                                                   const float* __restrict__ dinv,
                                                   const unsigned short* __restrict__ XW,
                                                   const float* __restrict__ b,
                                                   float* __restrict__ OUT, int N) {
    int c = blockIdx.x * 16 + (threadIdx.x >> 4);
    int j = threadIdx.x & 15;  // 8 features per lane
    if (c >= N) return;
    int e = rowptr[c], end = rowptr[c + 1];
    float acc[8] = {0.f, 0.f, 0.f, 0.f, 0.f, 0.f, 0.f, 0.f};
    const unsigned M = 0xffff0000u;
    for (; e + 1 < end; e += 2) {
        int r0 = srow[e], r1 = srow[e + 1];
        uint4 u0 = *reinterpret_cast<const uint4*>(XW + (size_t)r0 * HF + j * 8);
        uint4 u1 = *reinterpret_cast<const uint4*>(XW + (size_t)r1 * HF + j * 8);
        acc[0] += __uint_as_float(u0.x << 16) + __uint_as_float(u1.x << 16);
        acc[1] += __uint_as_float(u0.x & M)   + __uint_as_float(u1.x & M);
        acc[2] += __uint_as_float(u0.y << 16) + __uint_as_float(u1.y << 16);
        acc[3] += __uint_as_float(u0.y & M)   + __uint_as_float(u1.y & M);
        acc[4] += __uint_as_float(u0.z << 16) + __uint_as_float(u1.z << 16);
        acc[5] += __uint_as_float(u0.z & M)   + __uint_as_float(u1.z & M);
        acc[6] += __uint_as_float(u0.w << 16) + __uint_as_float(u1.w << 16);
        acc[7] += __uint_as_float(u0.w & M)   + __uint_as_float(u1.w & M);
    }
    if (e < end) {
        int r0 = srow[e];
        uint4 u0 = *reinterpret_cast<const uint4*>(XW + (size_t)r0 * HF + j * 8);
        acc[0] += __uint_as_float(u0.x << 16);
        acc[1] += __uint_as_float(u0.x & M);
        acc[2] += __uint_as_float(u0.y << 16);
        acc[3] += __uint_as_float(u0.y & M);
        acc[4] += __uint_as_float(u0.z << 16);
        acc[5] += __uint_as_float(u0.z & M);
        acc[6] += __uint_as_float(u0.w << 16);
        acc[7] += __uint_as_float(u0.w & M);
    }
    float dc = dinv[c];
    uint4 xv = *reinterpret_cast<const uint4*>(XW + (size_t)c * HF + j * 8);
    acc[0] += __uint_as_float(xv.x << 16);
    acc[1] += __uint_as_float(xv.x & M);
    acc[2] += __uint_as_float(xv.y << 16);
    acc[3] += __uint_as_float(xv.y & M);
    acc[4] += __uint_as_float(xv.z << 16);
    acc[5] += __uint_as_float(xv.z & M);
    acc[6] += __uint_as_float(xv.w << 16);
    acc[7] += __uint_as_float(xv.w & M);
    float4 b0 = *reinterpret_cast<const float4*>(b + j * 8);
    float4 b1 = *reinterpret_cast<const float4*>(b + j * 8 + 4);
    float4 o0, o1;
    o0.x = dc * acc[0] + b0.x;
    o0.y = dc * acc[1] + b0.y;
    o0.z = dc * acc[2] + b0.z;
    o0.w = dc * acc[3] + b0.w;
    o1.x = dc * acc[4] + b1.x;
    o1.y = dc * acc[5] + b1.y;
    o1.z = dc * acc[6] + b1.z;
    o1.w = dc * acc[7] + b1.w;
    float* op = OUT + (size_t)c * HF + j * 8;
    *reinterpret_cast<float4*>(op) = o0;
    *reinterpret_cast<float4*>(op + 4) = o1;
}

// ---------- BN stats ----------
__global__ __launch_bounds__(128) void bn_stats(const float* __restrict__ Y,
                                                float* __restrict__ ssum,
                                                float* __restrict__ ssq, int N) {
    int t = threadIdx.x;
    float s = 0.f, sq = 0.f;
    for (int n = blockIdx.x; n < N; n += gridDim.x) {
        float v = Y[(size_t)n * HF + t];
        s += v;
        sq += v * v;
    }
    atomicAdd(&ssum[t], s);
    atomicAdd(&ssq[t], sq);
}

__global__ __launch_bounds__(128) void bn_finalize(const float* __restrict__ ssum,
                                                   const float* __restrict__ ssq,
                                                   const float* __restrict__ gamma,
                                                   const float* __restrict__ beta,
                                                   float* __restrict__ scale,
                                                   float* __restrict__ shift, int N) {
    int t = threadIdx.x;
    float invn = 1.0f / (float)N;
    float mu = ssum[t] * invn;
    float var = ssq[t] * invn - mu * mu;
    float sc = gamma[t] * rsqrtf(var + 1e-5f);
    scale[t] = sc;
    shift[t] = beta[t] - mu * sc;
}

// ---------- graph boundaries (batch sorted) ----------
__global__ void graph_bounds(const int* __restrict__ batch, int* __restrict__ gstart,
                             int N, int NG) {
    int g = blockIdx.x * blockDim.x + threadIdx.x;
    if (g > NG) return;
    int lo = 0, hi = N;
    while (lo < hi) {
        int mid = (lo + hi) >> 1;
        if (batch[mid] < g) lo = mid + 1; else hi = mid;
    }
    gstart[g] = lo;
}

// ---------- fused BN2+ReLU + mean/max/sum pool + classifier ----------
__global__ __launch_bounds__(256) void pool_classify(const float* __restrict__ B,
                                                     const int* __restrict__ gstart,
                                                     const float* __restrict__ scale,
                                                     const float* __restrict__ shift,
                                                     const float* __restrict__ Wc,
                                                     const float* __restrict__ bc,
                                                     float* __restrict__ out) {
    int g = blockIdx.x;
    int t = threadIdx.x & 127;
    int half = threadIdx.x >> 7;
    int s0 = gstart[g], s1 = gstart[g + 1];
    float sc = scale[t], sh = shift[t];
    float sum = 0.f, mx = 0.f;  // 0-init == empty-graph guard (post-ReLU v >= 0)
    for (int n = s0 + half; n < s1; n += 2) {
        float v = fmaxf(B[(size_t)n * HF + t] * sc + sh, 0.0f);
        sum += v;
        mx = fmaxf(mx, v);
    }
    __shared__ float shsum[2][HF], shmax[2][HF];
    __shared__ float red[3][HF];
    shsum[half][t] = sum;
    shmax[half][t] = mx;
    __syncthreads();
    if (half == 0) {
        sum += shsum[1][t];
        mx = fmaxf(mx, shmax[1][t]);
        float cntf = (float)(s1 - s0);
        float mean = sum / fmaxf(cntf, 1.0f);
        red[0][t] = mean * Wc[t * 3 + 0] + mx * Wc[(HF + t) * 3 + 0] + sum * Wc[(2 * HF + t) * 3 + 0];
        red[1][t] = mean * Wc[t * 3 + 1] + mx * Wc[(HF + t) * 3 + 1] + sum * Wc[(2 * HF + t) * 3 + 1];
        red[2][t] = mean * Wc[t * 3 + 2] + mx * Wc[(HF + t) * 3 + 2] + sum * Wc[(2 * HF + t) * 3 + 2];
    }
    __syncthreads();
    for (int o = 64; o > 0; o >>= 1) {
        if (half == 0 && t < o) {
            red[0][t] += red[0][t + o];
            red[1][t] += red[1][t + o];
            red[2][t] += red[2][t + o];
        }
        __syncthreads();
    }
    if (threadIdx.x < 3) out[g * 3 + threadIdx.x] = red[threadIdx.x][0] + bc[threadIdx.x];
}

extern "C" void kernel_launch(void* const* d_in, const int* in_sizes, int n_in,
                              void* d_out, int out_size, void* d_ws, size_t ws_size,
                              hipStream_t stream) {
    const float* x    = (const float*)d_in[0];
    const int*   ei   = (const int*)d_in[1];
    const int*   batch= (const int*)d_in[2];
    const float* W1   = (const float*)d_in[3];
    const float* b1   = (const float*)d_in[4];
    const float* g1   = (const float*)d_in[5];
    const float* be1  = (const float*)d_in[6];
    const float* W2   = (const float*)d_in[7];
    const float* b2   = (const float*)d_in[8];
    const float* g2   = (const float*)d_in[9];
    const float* be2  = (const float*)d_in[10];
    const float* Wc   = (const float*)d_in[11];
    const float* bc   = (const float*)d_in[12];
    float* out = (float*)d_out;

    const int N = in_sizes[0] / HF;
    const int E = in_sizes[1] / 2;
    const int NG = 256;
    const int* row = ei;
    const int* col = ei + E;
    const int total = N * HF;
    const int step = (N + NXCD - 1) / NXCD;
    const unsigned magic = (unsigned)(((1ULL << 32) + step - 1) / (unsigned)step);  // ceil(2^32/step)
    const int cap = (E * 3) / 8;  // 3x expected bucket size
    const int tpg = (step + TILE - 1) / TILE;  // tiles per coarse group

    // workspace carve-up (256B aligned)
    char* w = (char*)d_ws;
    size_t off = 0;
    auto alloc = [&](size_t bytes) -> void* {
        void* p = w + off;
        off += (bytes + 255) & ~(size_t)255;
        return p;
    };
    int*            cursor   = (int*)alloc(NXCD * 4);
    int*            cnt_in   = (int*)alloc((size_t)N * 4);
    float*          dinv     = (float*)alloc((size_t)N * 4);
    int*            rowptr   = (int*)alloc(((size_t)N + 1) * 4);
    int*            blocksum = (int*)alloc(256 * 4);
    int*            gstart   = (int*)alloc((NG + 1) * 4);
    int*            srow     = (int*)alloc((size_t)E * 4);
    float*          ssum     = (float*)alloc(HF * 4);       // \ zeroed together
    float*          ssq      = (float*)alloc(HF * 4);       // /
    float*          scale    = (float*)alloc(HF * 4);
    float*          shift    = (float*)alloc(HF * 4);
    unsigned short* A        = (unsigned short*)alloc((size_t)total * 2);  // dinv-scaled xw (bf16)
    float*          B        = (float*)alloc((size_t)total * 4);           // conv out (f32)
    // buckets (8*cap*4 = 19.2MB) alias A+B (38.4MB): dead before gemm1 writes A
    unsigned*       buckets  = (unsigned*)A;

    const int T256 = 256;
    int gridGa   = (N + 15) / 16;
    int gridGemm = (N + 15) / 16;
    int nb       = (N + 255) / 256;   // scan blocks (requires N <= 65536)
    int gridBkt  = (E + 2047) / 2048;
    int gridTile = NXCD * tpg;

    // --- CSR build (once; reused by both convs) ---
    hipMemsetAsync(cursor, 0, NXCD * 4, stream);
    bucket_edges<<<gridBkt, T256, 0, stream>>>(row, col, buckets, cursor, E, step, magic, cap);
    tile_hist<<<gridTile, T256, 0, stream>>>(buckets, cursor, cnt_in, step, cap);
    scan_pass1<<<nb, 256, 0, stream>>>(cnt_in, rowptr, blocksum, dinv, N);
    scan_pass23<<<nb, 256, 0, stream>>>(rowptr, blocksum, N, E, nb);
    tile_place<<<gridTile, T256, 0, stream>>>(buckets, cursor, rowptr, srow, step, cap);
    graph_bounds<<<2, 129, 0, stream>>>(batch, gstart, N, NG);

    // --- conv1 (GEMM output rows pre-scaled by dinv) ---
    gemm128<<<gridGemm, 128, 0, stream>>>(x, W1, A, nullptr, nullptr, dinv, N, 0);
    gather_conv<<<gridGa, T256, 0, stream>>>(rowptr, srow, dinv, A, b1, B, N);
    hipMemsetAsync(ssum, 0, 2 * ((HF * 4 + 255) & ~255), stream);
    bn_stats<<<512, 128, 0, stream>>>(B, ssum, ssq, N);
    bn_finalize<<<1, 128, 0, stream>>>(ssum, ssq, g1, be1, scale, shift, N);

    // --- conv2 (BN1+ReLU fused into gemm input load) ---
    gemm128<<<gridGemm, 128, 0, stream>>>(B, W2, A, scale, shift, dinv, N, 1);
    gather_conv<<<gridGa, T256, 0, stream>>>(rowptr, srow, dinv, A, b2, B, N);
    hipMemsetAsync(ssum, 0, 2 * ((HF * 4 + 255) & ~255), stream);
    bn_stats<<<512, 128, 0, stream>>>(B, ssum, ssq, N);
    bn_finalize<<<1, 128, 0, stream>>>(ssum, ssq, g2, be2, scale, shift, N);

    // --- fused BN2+ReLU + pooling + classifier ---
    pool_classify<<<NG, 256, 0, stream>>>(B, gstart, scale, shift, Wc, bc, out);
}

// Round 8
// 375.411 us; speedup vs baseline: 1.8754x; 1.8754x over previous
//
#include <hip/hip_runtime.h>

#define HF 128       // feature width (F == H == 128)
#define TILE 128     // cols per fine bucket
#define CAP2 6144    // entries per fine bucket (mean 4096 + 32 sigma)
#define NFINE_MAX 512
#define SORT_CHUNK 4096

__device__ __forceinline__ unsigned short f2bf(float f) {
    unsigned u = __float_as_uint(f);
    unsigned rounding = 0x7FFF + ((u >> 16) & 1);  // round-to-nearest-even
    return (unsigned short)((u + rounding) >> 16);
}

// ---------- single-pass block counting sort into fine 128-col buckets ----------
// Each block sorts 4096 edges by bucket (c>>7) in LDS, reserves global space with
// ONE cursor atomic per non-empty bucket, then flushes bucket-sorted entries so
// consecutive threads write consecutive addresses (full-line bursts, ~10-entry runs).
__global__ __launch_bounds__(256) void bucket_sort(const int* __restrict__ row,
                                                   const int* __restrict__ col,
                                                   unsigned* __restrict__ buckets,
                                                   int* __restrict__ cursor,  // stride 16 ints (1 line each)
                                                   int E, int nfine) {
    __shared__ int hist[NFINE_MAX], lbase[NFINE_MAX], gbase[NFINE_MAX], lofs[NFINE_MAX];
    __shared__ int s[512];
    __shared__ unsigned staged[SORT_CHUNK];
    __shared__ unsigned short sbkt[SORT_CHUNK];
    int t = threadIdx.x;
    for (int i = t; i < NFINE_MAX; i += 256) { hist[i] = 0; lofs[i] = 0; }
    __syncthreads();
    int e0 = blockIdx.x * SORT_CHUNK;
    int n = min(SORT_CHUNK, E - e0);
    // pass 1: LDS histogram
    for (int i = t; i < n; i += 256) {
        int c = col[e0 + i];
        atomicAdd(&hist[c >> 7], 1);
    }
    __syncthreads();
    // Blelloch exclusive scan of hist[0..512) -> lbase
    s[t] = hist[t];
    s[t + 256] = hist[t + 256];
    for (int o = 1; o < 512; o <<= 1) {
        __syncthreads();
        int idx = (t + 1) * (o << 1) - 1;
        if (idx < 512) s[idx] += s[idx - o];
    }
    __syncthreads();
    if (t == 0) s[511] = 0;
    for (int o = 256; o >= 1; o >>= 1) {
        __syncthreads();
        int idx = (t + 1) * (o << 1) - 1;
        if (idx < 512) { int tmp = s[idx - o]; s[idx - o] = s[idx]; s[idx] += tmp; }
    }
    __syncthreads();
    lbase[t] = s[t];
    lbase[t + 256] = s[t + 256];
    // reserve global space: one atomic per non-empty bucket
    for (int b = t; b < nfine; b += 256) {
        int cnt = hist[b];
        gbase[b] = cnt ? atomicAdd(&cursor[b * 16], cnt) : 0;
    }
    __syncthreads();
    // pass 2: place into LDS sorted by bucket (edges re-read: L2-hot)
    for (int i = t; i < n; i += 256) {
        int c = col[e0 + i];
        int r = row[e0 + i];
        int b = c >> 7;
        int pos = lbase[b] + atomicAdd(&lofs[b], 1);
        staged[pos] = ((unsigned)(c & 127) << 17) | (unsigned)r;
        sbkt[pos] = (unsigned short)b;
    }
    __syncthreads();
    // flush: consecutive i within a bucket -> consecutive global addresses
    for (int i = t; i < n; i += 256) {
        int b = sbkt[i];
        int pos = gbase[b] + (i - lbase[b]);
        if (pos < CAP2) buckets[(size_t)b * CAP2 + pos] = staged[i];
    }
}

// ---------- per-tile degree histogram: each block streams ONLY its own bucket ----------
__global__ __launch_bounds__(256) void tile_hist_fine(const unsigned* __restrict__ buckets,
                                                      const int* __restrict__ cursor,
                                                      int* __restrict__ cnt, int N) {
    int b = blockIdx.x;
    __shared__ int h[TILE];
    int t = threadIdx.x;
    if (t < TILE) h[t] = 0;
    __syncthreads();
    int sz = min(cursor[b * 16], CAP2);
    const unsigned* bk = buckets + (size_t)b * CAP2;
    for (int i = t; i < sz; i += 256) atomicAdd(&h[bk[i] >> 17], 1);
    __syncthreads();
    int c = b * TILE + t;
    if (t < TILE && c < N) cnt[c] = h[t];
}

// ---------- scan pass1 + dinv fused ----------
__global__ __launch_bounds__(256) void scan_pass1(const int* __restrict__ cnt,
                                                  int* __restrict__ rowptr,
                                                  int* __restrict__ blocksum,
                                                  float* __restrict__ dinv, int N) {
    __shared__ int s[256];
    int t = threadIdx.x;
    int i = blockIdx.x * 256 + t;
    int v = (i < N) ? cnt[i] : 0;
    if (i < N) dinv[i] = rsqrtf((float)v + 1.0f);
    s[t] = v;
    __syncthreads();
    for (int o = 1; o < 256; o <<= 1) {
        int tv = (t >= o) ? s[t - o] : 0;
        __syncthreads();
        s[t] += tv;
        __syncthreads();
    }
    if (i < N) rowptr[i] = s[t] - v;  // block-local exclusive
    if (t == 255) blocksum[blockIdx.x] = s[255];
}

// fused pass2+3: each block reduces blocksum[0..blockIdx) itself (nb <= 256)
__global__ __launch_bounds__(256) void scan_pass23(int* __restrict__ rowptr,
                                                   const int* __restrict__ blocksum,
                                                   int N, int E, int nb) {
    __shared__ int s[256];
    int t = threadIdx.x;
    s[t] = (t < nb && t < blockIdx.x) ? blocksum[t] : 0;
    __syncthreads();
    for (int o = 128; o > 0; o >>= 1) {
        if (t < o) s[t] += s[t + o];
        __syncthreads();
    }
    int base = s[0];
    int i = blockIdx.x * 256 + t;
    if (i < N) rowptr[i] += base;
    if (blockIdx.x == 0 && t == 0) rowptr[N] = E;
}

// ---------- per-tile place: rowptr-derived cursors, LDS stage, contiguous burst out ----------
__global__ __launch_bounds__(256) void tile_place_fine(const unsigned* __restrict__ buckets,
                                                       const int* __restrict__ cursor,
                                                       const int* __restrict__ rowptr,
                                                       int* __restrict__ srow, int N) {
    int b = blockIdx.x;
    __shared__ int cur[TILE];
    __shared__ int stage[CAP2];
    int t = threadIdx.x;
    int c0 = b * TILE;
    int ncols = min(TILE, N - c0);
    int base = rowptr[c0];
    int tot = rowptr[c0 + ncols] - base;
    if (t < ncols) cur[t] = rowptr[c0 + t] - base;
    __syncthreads();
    int sz = min(cursor[b * 16], CAP2);
    const unsigned* bk = buckets + (size_t)b * CAP2;
    for (int i = t; i < sz; i += 256) {
        unsigned p = bk[i];
        int pos = atomicAdd(&cur[p >> 17], 1);
        if (pos < CAP2) stage[pos] = (int)(p & 0x1FFFFu);
    }
    __syncthreads();
    if (tot > CAP2) tot = CAP2;  // statistically impossible; guards corruption
    for (int i = t; i < tot; i += 256) srow[base + i] = stage[i];
}

// ---------- GEMM: Y[N,128](bf16) = rowscale[r] * (BNReLU?(X[N,128]) @ W[128,128]) ----------
__global__ __launch_bounds__(128) void gemm128(const float* __restrict__ X,
                                               const float* __restrict__ W,
                                               unsigned short* __restrict__ Y,
                                               const float* __restrict__ scale,
                                               const float* __restrict__ shift,
                                               const float* __restrict__ rowscale,
                                               int N, int applyBN) {
    __shared__ float xs[16][HF];
    int t = threadIdx.x;
    int row0 = blockIdx.x * 16;
    float sc = applyBN ? scale[t] : 1.0f;
    float sh = applyBN ? shift[t] : 0.0f;
    for (int r = 0; r < 16; ++r) {
        int rr = row0 + r;
        float v = (rr < N) ? X[(size_t)rr * HF + t] : 0.0f;
        if (applyBN) v = fmaxf(v * sc + sh, 0.0f);
        xs[r][t] = v;
    }
    __syncthreads();
    for (int r0 = 0; r0 < 16; r0 += 4) {
        float a0 = 0.f, a1 = 0.f, a2 = 0.f, a3 = 0.f;
        #pragma unroll 8
        for (int f = 0; f < HF; ++f) {
            float w = W[f * HF + t];
            a0 += xs[r0 + 0][f] * w;
            a1 += xs[r0 + 1][f] * w;
            a2 += xs[r0 + 2][f] * w;
            a3 += xs[r0 + 3][f] * w;
        }
        int rr = row0 + r0;
        if (rr + 0 < N) Y[(size_t)(rr + 0) * HF + t] = f2bf(a0 * rowscale[rr + 0]);
        if (rr + 1 < N) Y[(size_t)(rr + 1) * HF + t] = f2bf(a1 * rowscale[rr + 1]);
        if (rr + 2 < N) Y[(size_t)(rr + 2) * HF + t] = f2bf(a2 * rowscale[rr + 2]);
        if (rr + 3 < N) Y[(size_t)(rr + 3) * HF + t] = f2bf(a3 * rowscale[rr + 3]);
    }
}

// ---------- gather-side conv on pre-scaled bf16 XWs ----------
__global__ __launch_bounds__(256) void gather_conv(const int* __restrict__ rowptr,
                                                   const int* __restrict__ srow,
                                                   const float* __restrict__ dinv,
                                                   const unsigned short* __restrict__ XW,
                                                   const float* __restrict__ b,
                                                   float* __restrict__ OUT, int N) {
    int c = blockIdx.x * 16 + (threadIdx.x >> 4);
    int j = threadIdx.x & 15;  // 8 features per lane
    if (c >= N) return;
    int e = rowptr[c], end = rowptr[c + 1];
    float acc[8] = {0.f, 0.f, 0.f, 0.f, 0.f, 0.f, 0.f, 0.f};
    const unsigned M = 0xffff0000u;
    for (; e + 1 < end; e += 2) {
        int r0 = srow[e], r1 = srow[e + 1];
        uint4 u0 = *reinterpret_cast<const uint4*>(XW + (size_t)r0 * HF + j * 8);
        uint4 u1 = *reinterpret_cast<const uint4*>(XW + (size_t)r1 * HF + j * 8);
        acc[0] += __uint_as_float(u0.x << 16) + __uint_as_float(u1.x << 16);
        acc[1] += __uint_as_float(u0.x & M)   + __uint_as_float(u1.x & M);
        acc[2] += __uint_as_float(u0.y << 16) + __uint_as_float(u1.y << 16);
        acc[3] += __uint_as_float(u0.y & M)   + __uint_as_float(u1.y & M);
        acc[4] += __uint_as_float(u0.z << 16) + __uint_as_float(u1.z << 16);
        acc[5] += __uint_as_float(u0.z & M)   + __uint_as_float(u1.z & M);
        acc[6] += __uint_as_float(u0.w << 16) + __uint_as_float(u1.w << 16);
        acc[7] += __uint_as_float(u0.w & M)   + __uint_as_float(u1.w & M);
    }
    if (e < end) {
        int r0 = srow[e];
        uint4 u0 = *reinterpret_cast<const uint4*>(XW + (size_t)r0 * HF + j * 8);
        acc[0] += __uint_as_float(u0.x << 16);
        acc[1] += __uint_as_float(u0.x & M);
        acc[2] += __uint_as_float(u0.y << 16);
        acc[3] += __uint_as_float(u0.y & M);
        acc[4] += __uint_as_float(u0.z << 16);
        acc[5] += __uint_as_float(u0.z & M);
        acc[6] += __uint_as_float(u0.w << 16);
        acc[7] += __uint_as_float(u0.w & M);
    }
    float dc = dinv[c];
    uint4 xv = *reinterpret_cast<const uint4*>(XW + (size_t)c * HF + j * 8);
    acc[0] += __uint_as_float(xv.x << 16);
    acc[1] += __uint_as_float(xv.x & M);
    acc[2] += __uint_as_float(xv.y << 16);
    acc[3] += __uint_as_float(xv.y & M);
    acc[4] += __uint_as_float(xv.z << 16);
    acc[5] += __uint_as_float(xv.z & M);
    acc[6] += __uint_as_float(xv.w << 16);
    acc[7] += __uint_as_float(xv.w & M);
    float4 b0 = *reinterpret_cast<const float4*>(b + j * 8);
    float4 b1 = *reinterpret_cast<const float4*>(b + j * 8 + 4);
    float4 o0, o1;
    o0.x = dc * acc[0] + b0.x;
    o0.y = dc * acc[1] + b0.y;
    o0.z = dc * acc[2] + b0.z;
    o0.w = dc * acc[3] + b0.w;
    o1.x = dc * acc[4] + b1.x;
    o1.y = dc * acc[5] + b1.y;
    o1.z = dc * acc[6] + b1.z;
    o1.w = dc * acc[7] + b1.w;
    float* op = OUT + (size_t)c * HF + j * 8;
    *reinterpret_cast<float4*>(op) = o0;
    *reinterpret_cast<float4*>(op + 4) = o1;
}

// ---------- BN stats ----------
__global__ __launch_bounds__(128) void bn_stats(const float* __restrict__ Y,
                                                float* __restrict__ ssum,
                                                float* __restrict__ ssq, int N) {
    int t = threadIdx.x;
    float s = 0.f, sq = 0.f;
    for (int n = blockIdx.x; n < N; n += gridDim.x) {
        float v = Y[(size_t)n * HF + t];
        s += v;
        sq += v * v;
    }
    atomicAdd(&ssum[t], s);
    atomicAdd(&ssq[t], sq);
}

__global__ __launch_bounds__(128) void bn_finalize(const float* __restrict__ ssum,
                                                   const float* __restrict__ ssq,
                                                   const float* __restrict__ gamma,
                                                   const float* __restrict__ beta,
                                                   float* __restrict__ scale,
                                                   float* __restrict__ shift, int N) {
    int t = threadIdx.x;
    float invn = 1.0f / (float)N;
    float mu = ssum[t] * invn;
    float var = ssq[t] * invn - mu * mu;
    float sc = gamma[t] * rsqrtf(var + 1e-5f);
    scale[t] = sc;
    shift[t] = beta[t] - mu * sc;
}

// ---------- graph boundaries (batch sorted) ----------
__global__ void graph_bounds(const int* __restrict__ batch, int* __restrict__ gstart,
                             int N, int NG) {
    int g = blockIdx.x * blockDim.x + threadIdx.x;
    if (g > NG) return;
    int lo = 0, hi = N;
    while (lo < hi) {
        int mid = (lo + hi) >> 1;
        if (batch[mid] < g) lo = mid + 1; else hi = mid;
    }
    gstart[g] = lo;
}

// ---------- fused BN2+ReLU + mean/max/sum pool + classifier ----------
__global__ __launch_bounds__(256) void pool_classify(const float* __restrict__ B,
                                                     const int* __restrict__ gstart,
                                                     const float* __restrict__ scale,
                                                     const float* __restrict__ shift,
                                                     const float* __restrict__ Wc,
                                                     const float* __restrict__ bc,
                                                     float* __restrict__ out) {
    int g = blockIdx.x;
    int t = threadIdx.x & 127;
    int half = threadIdx.x >> 7;
    int s0 = gstart[g], s1 = gstart[g + 1];
    float sc = scale[t], sh = shift[t];
    float sum = 0.f, mx = 0.f;  // 0-init == empty-graph guard (post-ReLU v >= 0)
    for (int n = s0 + half; n < s1; n += 2) {
        float v = fmaxf(B[(size_t)n * HF + t] * sc + sh, 0.0f);
        sum += v;
        mx = fmaxf(mx, v);
    }
    __shared__ float shsum[2][HF], shmax[2][HF];
    __shared__ float red[3][HF];
    shsum[half][t] = sum;
    shmax[half][t] = mx;
    __syncthreads();
    if (half == 0) {
        sum += shsum[1][t];
        mx = fmaxf(mx, shmax[1][t]);
        float cntf = (float)(s1 - s0);
        float mean = sum / fmaxf(cntf, 1.0f);
        red[0][t] = mean * Wc[t * 3 + 0] + mx * Wc[(HF + t) * 3 + 0] + sum * Wc[(2 * HF + t) * 3 + 0];
        red[1][t] = mean * Wc[t * 3 + 1] + mx * Wc[(HF + t) * 3 + 1] + sum * Wc[(2 * HF + t) * 3 + 1];
        red[2][t] = mean * Wc[t * 3 + 2] + mx * Wc[(HF + t) * 3 + 2] + sum * Wc[(2 * HF + t) * 3 + 2];
    }
    __syncthreads();
    for (int o = 64; o > 0; o >>= 1) {
        if (half == 0 && t < o) {
            red[0][t] += red[0][t + o];
            red[1][t] += red[1][t + o];
            red[2][t] += red[2][t + o];
        }
        __syncthreads();
    }
    if (threadIdx.x < 3) out[g * 3 + threadIdx.x] = red[threadIdx.x][0] + bc[threadIdx.x];
}

extern "C" void kernel_launch(void* const* d_in, const int* in_sizes, int n_in,
                              void* d_out, int out_size, void* d_ws, size_t ws_size,
                              hipStream_t stream) {
    const float* x    = (const float*)d_in[0];
    const int*   ei   = (const int*)d_in[1];
    const int*   batch= (const int*)d_in[2];
    const float* W1   = (const float*)d_in[3];
    const float* b1   = (const float*)d_in[4];
    const float* g1   = (const float*)d_in[5];
    const float* be1  = (const float*)d_in[6];
    const float* W2   = (const float*)d_in[7];
    const float* b2   = (const float*)d_in[8];
    const float* g2   = (const float*)d_in[9];
    const float* be2  = (const float*)d_in[10];
    const float* Wc   = (const float*)d_in[11];
    const float* bc   = (const float*)d_in[12];
    float* out = (float*)d_out;

    const int N = in_sizes[0] / HF;
    const int E = in_sizes[1] / 2;
    const int NG = 256;
    const int* row = ei;
    const int* col = ei + E;
    const int total = N * HF;
    const int nfine = (N + TILE - 1) / TILE;  // fine buckets (requires N <= 65536)

    // workspace carve-up (256B aligned)
    char* w = (char*)d_ws;
    size_t off = 0;
    auto alloc = [&](size_t bytes) -> void* {
        void* p = w + off;
        off += (bytes + 255) & ~(size_t)255;
        return p;
    };
    int*            cursor   = (int*)alloc((size_t)nfine * 16 * 4);  // 1 line per bucket
    int*            cnt_in   = (int*)alloc((size_t)N * 4);
    float*          dinv     = (float*)alloc((size_t)N * 4);
    int*            rowptr   = (int*)alloc(((size_t)N + 1) * 4);
    int*            blocksum = (int*)alloc(256 * 4);
    int*            gstart   = (int*)alloc((NG + 1) * 4);
    int*            srow     = (int*)alloc((size_t)E * 4);
    float*          ssum     = (float*)alloc(HF * 4);       // \ zeroed together
    float*          ssq      = (float*)alloc(HF * 4);       // /
    float*          scale    = (float*)alloc(HF * 4);
    float*          shift    = (float*)alloc(HF * 4);
    unsigned short* A        = (unsigned short*)alloc((size_t)total * 2);  // dinv-scaled xw (bf16)
    float*          B        = (float*)alloc((size_t)total * 4);           // conv out (f32)
    // buckets (nfine*CAP2*4 = 9.6MB) alias A (12.8MB): dead before gemm1 writes A
    unsigned*       buckets  = (unsigned*)A;

    const int T256 = 256;
    int gridGa   = (N + 15) / 16;
    int gridGemm = (N + 15) / 16;
    int nb       = (N + 255) / 256;   // scan blocks (requires N <= 65536)
    int gridSort = (E + SORT_CHUNK - 1) / SORT_CHUNK;

    // --- CSR build (once; reused by both convs) ---
    hipMemsetAsync(cursor, 0, (size_t)nfine * 16 * 4, stream);
    bucket_sort<<<gridSort, T256, 0, stream>>>(row, col, buckets, cursor, E, nfine);
    tile_hist_fine<<<nfine, T256, 0, stream>>>(buckets, cursor, cnt_in, N);
    scan_pass1<<<nb, 256, 0, stream>>>(cnt_in, rowptr, blocksum, dinv, N);
    scan_pass23<<<nb, 256, 0, stream>>>(rowptr, blocksum, N, E, nb);
    tile_place_fine<<<nfine, T256, 0, stream>>>(buckets, cursor, rowptr, srow, N);
    graph_bounds<<<2, 129, 0, stream>>>(batch, gstart, N, NG);

    // --- conv1 (GEMM output rows pre-scaled by dinv) ---
    gemm128<<<gridGemm, 128, 0, stream>>>(x, W1, A, nullptr, nullptr, dinv, N, 0);
    gather_conv<<<gridGa, T256, 0, stream>>>(rowptr, srow, dinv, A, b1, B, N);
    hipMemsetAsync(ssum, 0, 2 * ((HF * 4 + 255) & ~255), stream);
    bn_stats<<<512, 128, 0, stream>>>(B, ssum, ssq, N);
    bn_finalize<<<1, 128, 0, stream>>>(ssum, ssq, g1, be1, scale, shift, N);

    // --- conv2 (BN1+ReLU fused into gemm input load) ---
    gemm128<<<gridGemm, 128, 0, stream>>>(B, W2, A, scale, shift, dinv, N, 1);
    gather_conv<<<gridGa, T256, 0, stream>>>(rowptr, srow, dinv, A, b2, B, N);
    hipMemsetAsync(ssum, 0, 2 * ((HF * 4 + 255) & ~255), stream);
    bn_stats<<<512, 128, 0, stream>>>(B, ssum, ssq, N);
    bn_finalize<<<1, 128, 0, stream>>>(ssum, ssq, g2, be2, scale, shift, N);

    // --- fused BN2+ReLU + pooling + classifier ---
    pool_classify<<<NG, 256, 0, stream>>>(B, gstart, scale, shift, Wc, bc, out);
}

// Round 9
// 355.373 us; speedup vs baseline: 1.9811x; 1.0564x over previous
//
#include <hip/hip_runtime.h>

#define HF 128       // feature width (F == H == 128)
#define TILE 128     // cols per fine bucket
#define CAP2 6144    // entries per fine bucket (mean ~4096 + slack)
#define NFINE_MAX 512
#define SORT_CHUNK 4096

__device__ __forceinline__ unsigned short f2bf(float f) {
    unsigned u = __float_as_uint(f);
    unsigned rounding = 0x7FFF + ((u >> 16) & 1);  // round-to-nearest-even
    return (unsigned short)((u + rounding) >> 16);
}

// ---------- single-pass block counting sort into fine 128-col buckets ----------
__global__ __launch_bounds__(256) void bucket_sort(const int* __restrict__ row,
                                                   const int* __restrict__ col,
                                                   unsigned* __restrict__ buckets,
                                                   int* __restrict__ cursor,  // stride 16 ints
                                                   int E, int nfine) {
    __shared__ int hist[NFINE_MAX], lbase[NFINE_MAX], gbase[NFINE_MAX], lofs[NFINE_MAX];
    __shared__ int s[512];
    __shared__ unsigned staged[SORT_CHUNK];
    __shared__ unsigned short sbkt[SORT_CHUNK];
    int t = threadIdx.x;
    for (int i = t; i < NFINE_MAX; i += 256) { hist[i] = 0; lofs[i] = 0; }
    __syncthreads();
    int e0 = blockIdx.x * SORT_CHUNK;
    int n = min(SORT_CHUNK, E - e0);
    for (int i = t; i < n; i += 256) {
        int c = col[e0 + i];
        atomicAdd(&hist[c >> 7], 1);
    }
    __syncthreads();
    s[t] = hist[t];
    s[t + 256] = hist[t + 256];
    for (int o = 1; o < 512; o <<= 1) {
        __syncthreads();
        int idx = (t + 1) * (o << 1) - 1;
        if (idx < 512) s[idx] += s[idx - o];
    }
    __syncthreads();
    if (t == 0) s[511] = 0;
    for (int o = 256; o >= 1; o >>= 1) {
        __syncthreads();
        int idx = (t + 1) * (o << 1) - 1;
        if (idx < 512) { int tmp = s[idx - o]; s[idx - o] = s[idx]; s[idx] += tmp; }
    }
    __syncthreads();
    lbase[t] = s[t];
    lbase[t + 256] = s[t + 256];
    for (int b = t; b < nfine; b += 256) {
        int cnt = hist[b];
        gbase[b] = cnt ? atomicAdd(&cursor[b * 16], cnt) : 0;
    }
    __syncthreads();
    for (int i = t; i < n; i += 256) {
        int c = col[e0 + i];
        int r = row[e0 + i];
        int b = c >> 7;
        int pos = lbase[b] + atomicAdd(&lofs[b], 1);
        staged[pos] = ((unsigned)(c & 127) << 17) | (unsigned)r;
        sbkt[pos] = (unsigned short)b;
    }
    __syncthreads();
    for (int i = t; i < n; i += 256) {
        int b = sbkt[i];
        int pos = gbase[b] + (i - lbase[b]);
        if (pos < CAP2) buckets[(size_t)b * CAP2 + pos] = staged[i];
    }
}

// ---------- per-tile degree histogram ----------
__global__ __launch_bounds__(256) void tile_hist_fine(const unsigned* __restrict__ buckets,
                                                      const int* __restrict__ cursor,
                                                      int* __restrict__ cnt, int N) {
    int b = blockIdx.x;
    __shared__ int h[TILE];
    int t = threadIdx.x;
    if (t < TILE) h[t] = 0;
    __syncthreads();
    int sz = min(cursor[b * 16], CAP2);
    const unsigned* bk = buckets + (size_t)b * CAP2;
    for (int i = t; i < sz; i += 256) atomicAdd(&h[bk[i] >> 17], 1);
    __syncthreads();
    int c = b * TILE + t;
    if (t < TILE && c < N) cnt[c] = h[t];
}

// ---------- scan pass1 + dinv fused ----------
__global__ __launch_bounds__(256) void scan_pass1(const int* __restrict__ cnt,
                                                  int* __restrict__ rowptr,
                                                  int* __restrict__ blocksum,
                                                  float* __restrict__ dinv, int N) {
    __shared__ int s[256];
    int t = threadIdx.x;
    int i = blockIdx.x * 256 + t;
    int v = (i < N) ? cnt[i] : 0;
    if (i < N) dinv[i] = rsqrtf((float)v + 1.0f);
    s[t] = v;
    __syncthreads();
    for (int o = 1; o < 256; o <<= 1) {
        int tv = (t >= o) ? s[t - o] : 0;
        __syncthreads();
        s[t] += tv;
        __syncthreads();
    }
    if (i < N) rowptr[i] = s[t] - v;
    if (t == 255) blocksum[blockIdx.x] = s[255];
}

__global__ __launch_bounds__(256) void scan_pass23(int* __restrict__ rowptr,
                                                   const int* __restrict__ blocksum,
                                                   int N, int E, int nb) {
    __shared__ int s[256];
    int t = threadIdx.x;
    s[t] = (t < nb && t < blockIdx.x) ? blocksum[t] : 0;
    __syncthreads();
    for (int o = 128; o > 0; o >>= 1) {
        if (t < o) s[t] += s[t + o];
        __syncthreads();
    }
    int base = s[0];
    int i = blockIdx.x * 256 + t;
    if (i < N) rowptr[i] += base;
    if (blockIdx.x == 0 && t == 0) rowptr[N] = E;
}

// ---------- per-tile place ----------
__global__ __launch_bounds__(256) void tile_place_fine(const unsigned* __restrict__ buckets,
                                                       const int* __restrict__ cursor,
                                                       const int* __restrict__ rowptr,
                                                       int* __restrict__ srow, int N) {
    int b = blockIdx.x;
    __shared__ int cur[TILE];
    __shared__ int stage[CAP2];
    int t = threadIdx.x;
    int c0 = b * TILE;
    int ncols = min(TILE, N - c0);
    int base = rowptr[c0];
    int tot = rowptr[c0 + ncols] - base;
    if (t < ncols) cur[t] = rowptr[c0 + t] - base;
    __syncthreads();
    int sz = min(cursor[b * 16], CAP2);
    const unsigned* bk = buckets + (size_t)b * CAP2;
    for (int i = t; i < sz; i += 256) {
        unsigned p = bk[i];
        int pos = atomicAdd(&cur[p >> 17], 1);
        if (pos < CAP2) stage[pos] = (int)(p & 0x1FFFFu);
    }
    __syncthreads();
    if (tot > CAP2) tot = CAP2;
    for (int i = t; i < tot; i += 256) srow[base + i] = stage[i];
}

// ---------- register-tiled GEMM ----------
// Y[N,128](bf16) = rowscale[r] * (BNReLU?(X[N,128]) @ W[128,128])
// 256 threads; block tile 32 rows x 128 cols; thread tile 4x4.
// X staged TRANSPOSED in LDS (xst[f][r], pad 36 -> 16B-aligned b128 broadcast reads).
// Per k-step/thread: 1 ds_read_b128 + 1 global dwordx4 (W, L2-hot) + 16 FMA.
__global__ __launch_bounds__(256) void gemm_rt(const float* __restrict__ X,
                                               const float* __restrict__ W,
                                               unsigned short* __restrict__ Y,
                                               const float* __restrict__ scale,
                                               const float* __restrict__ shift,
                                               const float* __restrict__ rowscale,
                                               int N, int applyBN) {
    __shared__ float xst[HF][36];
    int t = threadIdx.x;
    int row0 = blockIdx.x * 32;
    {
        int f = t & 127;
        float sc = applyBN ? scale[f] : 1.0f;
        float sh = applyBN ? shift[f] : 0.0f;
        for (int r = (t >> 7); r < 32; r += 2) {
            int rr = row0 + r;
            float v = (rr < N) ? X[(size_t)rr * HF + f] : 0.0f;
            if (applyBN) v = fmaxf(v * sc + sh, 0.0f);
            xst[f][r] = v;
        }
    }
    __syncthreads();
    int cg = t & 31;   // col group -> cols 4*cg..+3
    int rg = t >> 5;   // row group -> rows 4*rg..+3
    int c0 = cg * 4;
    int r0 = rg * 4;
    float a00=0,a01=0,a02=0,a03=0, a10=0,a11=0,a12=0,a13=0;
    float a20=0,a21=0,a22=0,a23=0, a30=0,a31=0,a32=0,a33=0;
    const float4* Wv = reinterpret_cast<const float4*>(W);
    #pragma unroll 4
    for (int f = 0; f < HF; ++f) {
        float4 w = Wv[f * 32 + cg];
        float4 xv = *reinterpret_cast<const float4*>(&xst[f][r0]);
        a00 += xv.x * w.x; a01 += xv.x * w.y; a02 += xv.x * w.z; a03 += xv.x * w.w;
        a10 += xv.y * w.x; a11 += xv.y * w.y; a12 += xv.y * w.z; a13 += xv.y * w.w;
        a20 += xv.z * w.x; a21 += xv.z * w.y; a22 += xv.z * w.z; a23 += xv.z * w.w;
        a30 += xv.w * w.x; a31 += xv.w * w.y; a32 += xv.w * w.z; a33 += xv.w * w.w;
    }
    float acc[4][4] = {{a00,a01,a02,a03},{a10,a11,a12,a13},{a20,a21,a22,a23},{a30,a31,a32,a33}};
    #pragma unroll
    for (int i = 0; i < 4; ++i) {
        int rr = row0 + r0 + i;
        if (rr < N) {
            float rs = rowscale[rr];
            ushort4 o;
            o.x = f2bf(acc[i][0] * rs);
            o.y = f2bf(acc[i][1] * rs);
            o.z = f2bf(acc[i][2] * rs);
            o.w = f2bf(acc[i][3] * rs);
            *reinterpret_cast<ushort4*>(&Y[(size_t)rr * HF + c0]) = o;
        }
    }
}

// ---------- gather-side conv on pre-scaled bf16 XWs ----------
__global__ __launch_bounds__(256) void gather_conv(const int* __restrict__ rowptr,
                                                   const int* __restrict__ srow,
                                                   const float* __restrict__ dinv,
                                                   const unsigned short* __restrict__ XW,
                                                   const float* __restrict__ b,
                                                   float* __restrict__ OUT, int N) {
    int c = blockIdx.x * 16 + (threadIdx.x >> 4);
    int j = threadIdx.x & 15;  // 8 features per lane
    if (c >= N) return;
    int e = rowptr[c], end = rowptr[c + 1];
    float acc[8] = {0.f, 0.f, 0.f, 0.f, 0.f, 0.f, 0.f, 0.f};
    const unsigned M = 0xffff0000u;
    for (; e + 1 < end; e += 2) {
        int r0 = srow[e], r1 = srow[e + 1];
        uint4 u0 = *reinterpret_cast<const uint4*>(XW + (size_t)r0 * HF + j * 8);
        uint4 u1 = *reinterpret_cast<const uint4*>(XW + (size_t)r1 * HF + j * 8);
        acc[0] += __uint_as_float(u0.x << 16) + __uint_as_float(u1.x << 16);
        acc[1] += __uint_as_float(u0.x & M)   + __uint_as_float(u1.x & M);
        acc[2] += __uint_as_float(u0.y << 16) + __uint_as_float(u1.y << 16);
        acc[3] += __uint_as_float(u0.y & M)   + __uint_as_float(u1.y & M);
        acc[4] += __uint_as_float(u0.z << 16) + __uint_as_float(u1.z << 16);
        acc[5] += __uint_as_float(u0.z & M)   + __uint_as_float(u1.z & M);
        acc[6] += __uint_as_float(u0.w << 16) + __uint_as_float(u1.w << 16);
        acc[7] += __uint_as_float(u0.w & M)   + __uint_as_float(u1.w & M);
    }
    if (e < end) {
        int r0 = srow[e];
        uint4 u0 = *reinterpret_cast<const uint4*>(XW + (size_t)r0 * HF + j * 8);
        acc[0] += __uint_as_float(u0.x << 16);
        acc[1] += __uint_as_float(u0.x & M);
        acc[2] += __uint_as_float(u0.y << 16);
        acc[3] += __uint_as_float(u0.y & M);
        acc[4] += __uint_as_float(u0.z << 16);
        acc[5] += __uint_as_float(u0.z & M);
        acc[6] += __uint_as_float(u0.w << 16);
        acc[7] += __uint_as_float(u0.w & M);
    }
    float dc = dinv[c];
    uint4 xv = *reinterpret_cast<const uint4*>(XW + (size_t)c * HF + j * 8);
    acc[0] += __uint_as_float(xv.x << 16);
    acc[1] += __uint_as_float(xv.x & M);
    acc[2] += __uint_as_float(xv.y << 16);
    acc[3] += __uint_as_float(xv.y & M);
    acc[4] += __uint_as_float(xv.z << 16);
    acc[5] += __uint_as_float(xv.z & M);
    acc[6] += __uint_as_float(xv.w << 16);
    acc[7] += __uint_as_float(xv.w & M);
    float4 b0 = *reinterpret_cast<const float4*>(b + j * 8);
    float4 b1 = *reinterpret_cast<const float4*>(b + j * 8 + 4);
    float4 o0, o1;
    o0.x = dc * acc[0] + b0.x;
    o0.y = dc * acc[1] + b0.y;
    o0.z = dc * acc[2] + b0.z;
    o0.w = dc * acc[3] + b0.w;
    o1.x = dc * acc[4] + b1.x;
    o1.y = dc * acc[5] + b1.y;
    o1.z = dc * acc[6] + b1.z;
    o1.w = dc * acc[7] + b1.w;
    float* op = OUT + (size_t)c * HF + j * 8;
    *reinterpret_cast<float4*>(op) = o0;
    *reinterpret_cast<float4*>(op + 4) = o1;
}

// ---------- BN stats ----------
__global__ __launch_bounds__(128) void bn_stats(const float* __restrict__ Y,
                                                float* __restrict__ ssum,
                                                float* __restrict__ ssq, int N) {
    int t = threadIdx.x;
    float s = 0.f, sq = 0.f;
    for (int n = blockIdx.x; n < N; n += gridDim.x) {
        float v = Y[(size_t)n * HF + t];
        s += v;
        sq += v * v;
    }
    atomicAdd(&ssum[t], s);
    atomicAdd(&ssq[t], sq);
}

__global__ __launch_bounds__(128) void bn_finalize(const float* __restrict__ ssum,
                                                   const float* __restrict__ ssq,
                                                   const float* __restrict__ gamma,
                                                   const float* __restrict__ beta,
                                                   float* __restrict__ scale,
                                                   float* __restrict__ shift, int N) {
    int t = threadIdx.x;
    float invn = 1.0f / (float)N;
    float mu = ssum[t] * invn;
    float var = ssq[t] * invn - mu * mu;
    float sc = gamma[t] * rsqrtf(var + 1e-5f);
    scale[t] = sc;
    shift[t] = beta[t] - mu * sc;
}

// ---------- graph boundaries (batch sorted) ----------
__global__ void graph_bounds(const int* __restrict__ batch, int* __restrict__ gstart,
                             int N, int NG) {
    int g = blockIdx.x * blockDim.x + threadIdx.x;
    if (g > NG) return;
    int lo = 0, hi = N;
    while (lo < hi) {
        int mid = (lo + hi) >> 1;
        if (batch[mid] < g) lo = mid + 1; else hi = mid;
    }
    gstart[g] = lo;
}

// ---------- fused BN2+ReLU + mean/max/sum pool + classifier ----------
__global__ __launch_bounds__(256) void pool_classify(const float* __restrict__ B,
                                                     const int* __restrict__ gstart,
                                                     const float* __restrict__ scale,
                                                     const float* __restrict__ shift,
                                                     const float* __restrict__ Wc,
                                                     const float* __restrict__ bc,
                                                     float* __restrict__ out) {
    int g = blockIdx.x;
    int t = threadIdx.x & 127;
    int half = threadIdx.x >> 7;
    int s0 = gstart[g], s1 = gstart[g + 1];
    float sc = scale[t], sh = shift[t];
    float sum = 0.f, mx = 0.f;  // 0-init == empty-graph guard (post-ReLU v >= 0)
    for (int n = s0 + half; n < s1; n += 2) {
        float v = fmaxf(B[(size_t)n * HF + t] * sc + sh, 0.0f);
        sum += v;
        mx = fmaxf(mx, v);
    }
    __shared__ float shsum[2][HF], shmax[2][HF];
    __shared__ float red[3][HF];
    shsum[half][t] = sum;
    shmax[half][t] = mx;
    __syncthreads();
    if (half == 0) {
        sum += shsum[1][t];
        mx = fmaxf(mx, shmax[1][t]);
        float cntf = (float)(s1 - s0);
        float mean = sum / fmaxf(cntf, 1.0f);
        red[0][t] = mean * Wc[t * 3 + 0] + mx * Wc[(HF + t) * 3 + 0] + sum * Wc[(2 * HF + t) * 3 + 0];
        red[1][t] = mean * Wc[t * 3 + 1] + mx * Wc[(HF + t) * 3 + 1] + sum * Wc[(2 * HF + t) * 3 + 1];
        red[2][t] = mean * Wc[t * 3 + 2] + mx * Wc[(HF + t) * 3 + 2] + sum * Wc[(2 * HF + t) * 3 + 2];
    }
    __syncthreads();
    for (int o = 64; o > 0; o >>= 1) {
        if (half == 0 && t < o) {
            red[0][t] += red[0][t + o];
            red[1][t] += red[1][t + o];
            red[2][t] += red[2][t + o];
        }
        __syncthreads();
    }
    if (threadIdx.x < 3) out[g * 3 + threadIdx.x] = red[threadIdx.x][0] + bc[threadIdx.x];
}

extern "C" void kernel_launch(void* const* d_in, const int* in_sizes, int n_in,
                              void* d_out, int out_size, void* d_ws, size_t ws_size,
                              hipStream_t stream) {
    const float* x    = (const float*)d_in[0];
    const int*   ei   = (const int*)d_in[1];
    const int*   batch= (const int*)d_in[2];
    const float* W1   = (const float*)d_in[3];
    const float* b1   = (const float*)d_in[4];
    const float* g1   = (const float*)d_in[5];
    const float* be1  = (const float*)d_in[6];
    const float* W2   = (const float*)d_in[7];
    const float* b2   = (const float*)d_in[8];
    const float* g2   = (const float*)d_in[9];
    const float* be2  = (const float*)d_in[10];
    const float* Wc   = (const float*)d_in[11];
    const float* bc   = (const float*)d_in[12];
    float* out = (float*)d_out;

    const int N = in_sizes[0] / HF;
    const int E = in_sizes[1] / 2;
    const int NG = 256;
    const int* row = ei;
    const int* col = ei + E;
    const int total = N * HF;
    const int nfine = (N + TILE - 1) / TILE;

    // workspace carve-up (256B aligned)
    char* w = (char*)d_ws;
    size_t off = 0;
    auto alloc = [&](size_t bytes) -> void* {
        void* p = w + off;
        off += (bytes + 255) & ~(size_t)255;
        return p;
    };
    int*            cursor   = (int*)alloc((size_t)nfine * 16 * 4);
    int*            cnt_in   = (int*)alloc((size_t)N * 4);
    float*          dinv     = (float*)alloc((size_t)N * 4);
    int*            rowptr   = (int*)alloc(((size_t)N + 1) * 4);
    int*            blocksum = (int*)alloc(256 * 4);
    int*            gstart   = (int*)alloc((NG + 1) * 4);
    int*            srow     = (int*)alloc((size_t)E * 4);
    float*          ssum     = (float*)alloc(HF * 4);
    float*          ssq      = (float*)alloc(HF * 4);
    float*          scale    = (float*)alloc(HF * 4);
    float*          shift    = (float*)alloc(HF * 4);
    unsigned short* A        = (unsigned short*)alloc((size_t)total * 2);  // dinv-scaled xw (bf16)
    float*          B        = (float*)alloc((size_t)total * 4);           // conv out (f32)
    unsigned*       buckets  = (unsigned*)A;  // aliases A (dead before gemm1)

    const int T256 = 256;
    int gridGa   = (N + 15) / 16;
    int gridGemm = (N + 31) / 32;
    int nb       = (N + 255) / 256;
    int gridSort = (E + SORT_CHUNK - 1) / SORT_CHUNK;

    // --- CSR build (once; reused by both convs) ---
    hipMemsetAsync(cursor, 0, (size_t)nfine * 16 * 4, stream);
    bucket_sort<<<gridSort, T256, 0, stream>>>(row, col, buckets, cursor, E, nfine);
    tile_hist_fine<<<nfine, T256, 0, stream>>>(buckets, cursor, cnt_in, N);
    scan_pass1<<<nb, 256, 0, stream>>>(cnt_in, rowptr, blocksum, dinv, N);
    scan_pass23<<<nb, 256, 0, stream>>>(rowptr, blocksum, N, E, nb);
    tile_place_fine<<<nfine, T256, 0, stream>>>(buckets, cursor, rowptr, srow, N);
    graph_bounds<<<2, 129, 0, stream>>>(batch, gstart, N, NG);

    // --- conv1 (GEMM output rows pre-scaled by dinv) ---
    gemm_rt<<<gridGemm, T256, 0, stream>>>(x, W1, A, nullptr, nullptr, dinv, N, 0);
    gather_conv<<<gridGa, T256, 0, stream>>>(rowptr, srow, dinv, A, b1, B, N);
    hipMemsetAsync(ssum, 0, 2 * ((HF * 4 + 255) & ~255), stream);
    bn_stats<<<512, 128, 0, stream>>>(B, ssum, ssq, N);
    bn_finalize<<<1, 128, 0, stream>>>(ssum, ssq, g1, be1, scale, shift, N);

    // --- conv2 (BN1+ReLU fused into gemm input load) ---
    gemm_rt<<<gridGemm, T256, 0, stream>>>(B, W2, A, scale, shift, dinv, N, 1);
    gather_conv<<<gridGa, T256, 0, stream>>>(rowptr, srow, dinv, A, b2, B, N);
    hipMemsetAsync(ssum, 0, 2 * ((HF * 4 + 255) & ~255), stream);
    bn_stats<<<512, 128, 0, stream>>>(B, ssum, ssq, N);
    bn_finalize<<<1, 128, 0, stream>>>(ssum, ssq, g2, be2, scale, shift, N);

    // --- fused BN2+ReLU + pooling + classifier ---
    pool_classify<<<NG, 256, 0, stream>>>(B, gstart, scale, shift, Wc, bc, out);
}

// Round 11
// 351.099 us; speedup vs baseline: 2.0052x; 1.0122x over previous
//
#include <hip/hip_runtime.h>

#define HF 128       // feature width (F == H == 128)
#define TILE 128     // cols per fine bucket
#define CAP2 6144    // entries per fine bucket (mean ~4096 + slack)
#define NFINE_MAX 512
#define SORT_CHUNK 4096

__device__ __forceinline__ unsigned short f2bf(float f) {
    unsigned u = __float_as_uint(f);
    unsigned rounding = 0x7FFF + ((u >> 16) & 1);  // round-to-nearest-even
    return (unsigned short)((u + rounding) >> 16);
}

// ---------- single-pass block counting sort into fine 128-col buckets ----------
__global__ __launch_bounds__(256) void bucket_sort(const int* __restrict__ row,
                                                   const int* __restrict__ col,
                                                   unsigned* __restrict__ buckets,
                                                   int* __restrict__ cursor,  // stride 16 ints
                                                   int E, int nfine) {
    __shared__ int hist[NFINE_MAX], lbase[NFINE_MAX], gbase[NFINE_MAX], lofs[NFINE_MAX];
    __shared__ int s[512];
    __shared__ unsigned staged[SORT_CHUNK];
    __shared__ unsigned short sbkt[SORT_CHUNK];
    int t = threadIdx.x;
    for (int i = t; i < NFINE_MAX; i += 256) { hist[i] = 0; lofs[i] = 0; }
    __syncthreads();
    int e0 = blockIdx.x * SORT_CHUNK;
    int n = min(SORT_CHUNK, E - e0);
    for (int i = t; i < n; i += 256) {
        int c = col[e0 + i];
        atomicAdd(&hist[c >> 7], 1);
    }
    __syncthreads();
    s[t] = hist[t];
    s[t + 256] = hist[t + 256];
    for (int o = 1; o < 512; o <<= 1) {
        __syncthreads();
        int idx = (t + 1) * (o << 1) - 1;
        if (idx < 512) s[idx] += s[idx - o];
    }
    __syncthreads();
    if (t == 0) s[511] = 0;
    for (int o = 256; o >= 1; o >>= 1) {
        __syncthreads();
        int idx = (t + 1) * (o << 1) - 1;
        if (idx < 512) { int tmp = s[idx - o]; s[idx - o] = s[idx]; s[idx] += tmp; }
    }
    __syncthreads();
    lbase[t] = s[t];
    lbase[t + 256] = s[t + 256];
    for (int b = t; b < nfine; b += 256) {
        int cnt = hist[b];
        gbase[b] = cnt ? atomicAdd(&cursor[b * 16], cnt) : 0;
    }
    __syncthreads();
    for (int i = t; i < n; i += 256) {
        int c = col[e0 + i];
        int r = row[e0 + i];
        int b = c >> 7;
        int pos = lbase[b] + atomicAdd(&lofs[b], 1);
        staged[pos] = ((unsigned)(c & 127) << 17) | (unsigned)r;
        sbkt[pos] = (unsigned short)b;
    }
    __syncthreads();
    for (int i = t; i < n; i += 256) {
        int b = sbkt[i];
        int pos = gbase[b] + (i - lbase[b]);
        if (pos < CAP2) buckets[(size_t)b * CAP2 + pos] = staged[i];
    }
}

// ---------- per-tile degree histogram ----------
__global__ __launch_bounds__(256) void tile_hist_fine(const unsigned* __restrict__ buckets,
                                                      const int* __restrict__ cursor,
                                                      int* __restrict__ cnt, int N) {
    int b = blockIdx.x;
    __shared__ int h[TILE];
    int t = threadIdx.x;
    if (t < TILE) h[t] = 0;
    __syncthreads();
    int sz = min(cursor[b * 16], CAP2);
    const unsigned* bk = buckets + (size_t)b * CAP2;
    for (int i = t; i < sz; i += 256) atomicAdd(&h[bk[i] >> 17], 1);
    __syncthreads();
    int c = b * TILE + t;
    if (t < TILE && c < N) cnt[c] = h[t];
}

// ---------- scan pass1 + dinv fused ----------
__global__ __launch_bounds__(256) void scan_pass1(const int* __restrict__ cnt,
                                                  int* __restrict__ rowptr,
                                                  int* __restrict__ blocksum,
                                                  float* __restrict__ dinv, int N) {
    __shared__ int s[256];
    int t = threadIdx.x;
    int i = blockIdx.x * 256 + t;
    int v = (i < N) ? cnt[i] : 0;
    if (i < N) dinv[i] = rsqrtf((float)v + 1.0f);
    s[t] = v;
    __syncthreads();
    for (int o = 1; o < 256; o <<= 1) {
        int tv = (t >= o) ? s[t - o] : 0;
        __syncthreads();
        s[t] += tv;
        __syncthreads();
    }
    if (i < N) rowptr[i] = s[t] - v;
    if (t == 255) blocksum[blockIdx.x] = s[255];
}

__global__ __launch_bounds__(256) void scan_pass23(int* __restrict__ rowptr,
                                                   const int* __restrict__ blocksum,
                                                   int N, int E, int nb) {
    __shared__ int s[256];
    int t = threadIdx.x;
    s[t] = (t < nb && t < blockIdx.x) ? blocksum[t] : 0;
    __syncthreads();
    for (int o = 128; o > 0; o >>= 1) {
        if (t < o) s[t] += s[t + o];
        __syncthreads();
    }
    int base = s[0];
    int i = blockIdx.x * 256 + t;
    if (i < N) rowptr[i] += base;
    if (blockIdx.x == 0 && t == 0) rowptr[N] = E;
}

// ---------- per-tile place ----------
__global__ __launch_bounds__(256) void tile_place_fine(const unsigned* __restrict__ buckets,
                                                       const int* __restrict__ cursor,
                                                       const int* __restrict__ rowptr,
                                                       int* __restrict__ srow, int N) {
    int b = blockIdx.x;
    __shared__ int cur[TILE];
    __shared__ int stage[CAP2];
    int t = threadIdx.x;
    int c0 = b * TILE;
    int ncols = min(TILE, N - c0);
    int base = rowptr[c0];
    int tot = rowptr[c0 + ncols] - base;
    if (t < ncols) cur[t] = rowptr[c0 + t] - base;
    __syncthreads();
    int sz = min(cursor[b * 16], CAP2);
    const unsigned* bk = buckets + (size_t)b * CAP2;
    for (int i = t; i < sz; i += 256) {
        unsigned p = bk[i];
        int pos = atomicAdd(&cur[p >> 17], 1);
        if (pos < CAP2) stage[pos] = (int)(p & 0x1FFFFu);
    }
    __syncthreads();
    if (tot > CAP2) tot = CAP2;
    for (int i = t; i < tot; i += 256) srow[base + i] = stage[i];
}

// ---------- register-tiled GEMM ----------
__global__ __launch_bounds__(256) void gemm_rt(const float* __restrict__ X,
                                               const float* __restrict__ W,
                                               unsigned short* __restrict__ Y,
                                               const float* __restrict__ scale,
                                               const float* __restrict__ shift,
                                               const float* __restrict__ rowscale,
                                               int N, int applyBN) {
    __shared__ float xst[HF][36];
    int t = threadIdx.x;
    int row0 = blockIdx.x * 32;
    {
        int f = t & 127;
        float sc = applyBN ? scale[f] : 1.0f;
        float sh = applyBN ? shift[f] : 0.0f;
        for (int r = (t >> 7); r < 32; r += 2) {
            int rr = row0 + r;
            float v = (rr < N) ? X[(size_t)rr * HF + f] : 0.0f;
            if (applyBN) v = fmaxf(v * sc + sh, 0.0f);
            xst[f][r] = v;
        }
    }
    __syncthreads();
    int cg = t & 31;
    int rg = t >> 5;
    int c0 = cg * 4;
    int r0 = rg * 4;
    float a00=0,a01=0,a02=0,a03=0, a10=0,a11=0,a12=0,a13=0;
    float a20=0,a21=0,a22=0,a23=0, a30=0,a31=0,a32=0,a33=0;
    const float4* Wv = reinterpret_cast<const float4*>(W);
    #pragma unroll 4
    for (int f = 0; f < HF; ++f) {
        float4 w = Wv[f * 32 + cg];
        float4 xv = *reinterpret_cast<const float4*>(&xst[f][r0]);
        a00 += xv.x * w.x; a01 += xv.x * w.y; a02 += xv.x * w.z; a03 += xv.x * w.w;
        a10 += xv.y * w.x; a11 += xv.y * w.y; a12 += xv.y * w.z; a13 += xv.y * w.w;
        a20 += xv.z * w.x; a21 += xv.z * w.y; a22 += xv.z * w.z; a23 += xv.z * w.w;
        a30 += xv.w * w.x; a31 += xv.w * w.y; a32 += xv.w * w.z; a33 += xv.w * w.w;
    }
    float acc[4][4] = {{a00,a01,a02,a03},{a10,a11,a12,a13},{a20,a21,a22,a23},{a30,a31,a32,a33}};
    #pragma unroll
    for (int i = 0; i < 4; ++i) {
        int rr = row0 + r0 + i;
        if (rr < N) {
            float rs = rowscale[rr];
            ushort4 o;
            o.x = f2bf(acc[i][0] * rs);
            o.y = f2bf(acc[i][1] * rs);
            o.z = f2bf(acc[i][2] * rs);
            o.w = f2bf(acc[i][3] * rs);
            *reinterpret_cast<ushort4*>(&Y[(size_t)rr * HF + c0]) = o;
        }
    }
}

// ---------- gather-side conv on pre-scaled bf16 XWs (4-deep edge unroll) ----------
__global__ __launch_bounds__(256) void gather_conv(const int* __restrict__ rowptr,
                                                   const int* __restrict__ srow,
                                                   const float* __restrict__ dinv,
                                                   const unsigned short* __restrict__ XW,
                                                   const float* __restrict__ b,
                                                   float* __restrict__ OUT, int N) {
    int c = blockIdx.x * 16 + (threadIdx.x >> 4);
    int j = threadIdx.x & 15;  // 8 features per lane
    if (c >= N) return;
    int e = rowptr[c], end = rowptr[c + 1];
    float acc[8] = {0.f, 0.f, 0.f, 0.f, 0.f, 0.f, 0.f, 0.f};
    const unsigned M = 0xffff0000u;
    for (; e + 3 < end; e += 4) {
        int r0 = srow[e], r1 = srow[e + 1], r2 = srow[e + 2], r3 = srow[e + 3];
        uint4 u0 = *reinterpret_cast<const uint4*>(XW + (size_t)r0 * HF + j * 8);
        uint4 u1 = *reinterpret_cast<const uint4*>(XW + (size_t)r1 * HF + j * 8);
        uint4 u2 = *reinterpret_cast<const uint4*>(XW + (size_t)r2 * HF + j * 8);
        uint4 u3 = *reinterpret_cast<const uint4*>(XW + (size_t)r3 * HF + j * 8);
        acc[0] += (__uint_as_float(u0.x << 16) + __uint_as_float(u1.x << 16))
                + (__uint_as_float(u2.x << 16) + __uint_as_float(u3.x << 16));
        acc[1] += (__uint_as_float(u0.x & M) + __uint_as_float(u1.x & M))
                + (__uint_as_float(u2.x & M) + __uint_as_float(u3.x & M));
        acc[2] += (__uint_as_float(u0.y << 16) + __uint_as_float(u1.y << 16))
                + (__uint_as_float(u2.y << 16) + __uint_as_float(u3.y << 16));
        acc[3] += (__uint_as_float(u0.y & M) + __uint_as_float(u1.y & M))
                + (__uint_as_float(u2.y & M) + __uint_as_float(u3.y & M));
        acc[4] += (__uint_as_float(u0.z << 16) + __uint_as_float(u1.z << 16))
                + (__uint_as_float(u2.z << 16) + __uint_as_float(u3.z << 16));
        acc[5] += (__uint_as_float(u0.z & M) + __uint_as_float(u1.z & M))
                + (__uint_as_float(u2.z & M) + __uint_as_float(u3.z & M));
        acc[6] += (__uint_as_float(u0.w << 16) + __uint_as_float(u1.w << 16))
                + (__uint_as_float(u2.w << 16) + __uint_as_float(u3.w << 16));
        acc[7] += (__uint_as_float(u0.w & M) + __uint_as_float(u1.w & M))
                + (__uint_as_float(u2.w & M) + __uint_as_float(u3.w & M));
    }
    for (; e < end; ++e) {
        int r0 = srow[e];
        uint4 u0 = *reinterpret_cast<const uint4*>(XW + (size_t)r0 * HF + j * 8);
        acc[0] += __uint_as_float(u0.x << 16);
        acc[1] += __uint_as_float(u0.x & M);
        acc[2] += __uint_as_float(u0.y << 16);
        acc[3] += __uint_as_float(u0.y & M);
        acc[4] += __uint_as_float(u0.z << 16);
        acc[5] += __uint_as_float(u0.z & M);
        acc[6] += __uint_as_float(u0.w << 16);
        acc[7] += __uint_as_float(u0.w & M);
    }
    float dc = dinv[c];
    uint4 xv = *reinterpret_cast<const uint4*>(XW + (size_t)c * HF + j * 8);
    acc[0] += __uint_as_float(xv.x << 16);
    acc[1] += __uint_as_float(xv.x & M);
    acc[2] += __uint_as_float(xv.y << 16);
    acc[3] += __uint_as_float(xv.y & M);
    acc[4] += __uint_as_float(xv.z << 16);
    acc[5] += __uint_as_float(xv.z & M);
    acc[6] += __uint_as_float(xv.w << 16);
    acc[7] += __uint_as_float(xv.w & M);
    float4 b0 = *reinterpret_cast<const float4*>(b + j * 8);
    float4 b1 = *reinterpret_cast<const float4*>(b + j * 8 + 4);
    float4 o0, o1;
    o0.x = dc * acc[0] + b0.x;
    o0.y = dc * acc[1] + b0.y;
    o0.z = dc * acc[2] + b0.z;
    o0.w = dc * acc[3] + b0.w;
    o1.x = dc * acc[4] + b1.x;
    o1.y = dc * acc[5] + b1.y;
    o1.z = dc * acc[6] + b1.z;
    o1.w = dc * acc[7] + b1.w;
    float* op = OUT + (size_t)c * HF + j * 8;
    *reinterpret_cast<float4*>(op) = o0;
    *reinterpret_cast<float4*>(op + 4) = o1;
}

// ---------- BN stats ----------
__global__ __launch_bounds__(128) void bn_stats(const float* __restrict__ Y,
                                                float* __restrict__ ssum,
                                                float* __restrict__ ssq, int N) {
    int t = threadIdx.x;
    float s = 0.f, sq = 0.f;
    for (int n = blockIdx.x; n < N; n += gridDim.x) {
        float v = Y[(size_t)n * HF + t];
        s += v;
        sq += v * v;
    }
    atomicAdd(&ssum[t], s);
    atomicAdd(&ssq[t], sq);
}

__global__ __launch_bounds__(128) void bn_finalize(const float* __restrict__ ssum,
                                                   const float* __restrict__ ssq,
                                                   const float* __restrict__ gamma,
                                                   const float* __restrict__ beta,
                                                   float* __restrict__ scale,
                                                   float* __restrict__ shift, int N) {
    int t = threadIdx.x;
    float invn = 1.0f / (float)N;
    float mu = ssum[t] * invn;
    float var = ssq[t] * invn - mu * mu;
    float sc = gamma[t] * rsqrtf(var + 1e-5f);
    scale[t] = sc;
    shift[t] = beta[t] - mu * sc;
}

// ---------- graph boundaries (batch sorted) ----------
__global__ void graph_bounds(const int* __restrict__ batch, int* __restrict__ gstart,
                             int N, int NG) {
    int g = blockIdx.x * blockDim.x + threadIdx.x;
    if (g > NG) return;
    int lo = 0, hi = N;
    while (lo < hi) {
        int mid = (lo + hi) >> 1;
        if (batch[mid] < g) lo = mid + 1; else hi = mid;
    }
    gstart[g] = lo;
}

// ---------- fused BN2+ReLU + mean/max/sum pool + classifier ----------
__global__ __launch_bounds__(256) void pool_classify(const float* __restrict__ B,
                                                     const int* __restrict__ gstart,
                                                     const float* __restrict__ scale,
                                                     const float* __restrict__ shift,
                                                     const float* __restrict__ Wc,
                                                     const float* __restrict__ bc,
                                                     float* __restrict__ out) {
    int g = blockIdx.x;
    int t = threadIdx.x & 127;
    int half = threadIdx.x >> 7;
    int s0 = gstart[g], s1 = gstart[g + 1];
    float sc = scale[t], sh = shift[t];
    float sum = 0.f, mx = 0.f;  // 0-init == empty-graph guard (post-ReLU v >= 0)
    for (int n = s0 + half; n < s1; n += 2) {
        float v = fmaxf(B[(size_t)n * HF + t] * sc + sh, 0.0f);
        sum += v;
        mx = fmaxf(mx, v);
    }
    __shared__ float shsum[2][HF], shmax[2][HF];
    __shared__ float red[3][HF];
    shsum[half][t] = sum;
    shmax[half][t] = mx;
    __syncthreads();
    if (half == 0) {
        sum += shsum[1][t];
        mx = fmaxf(mx, shmax[1][t]);
        float cntf = (float)(s1 - s0);
        float mean = sum / fmaxf(cntf, 1.0f);
        red[0][t] = mean * Wc[t * 3 + 0] + mx * Wc[(HF + t) * 3 + 0] + sum * Wc[(2 * HF + t) * 3 + 0];
        red[1][t] = mean * Wc[t * 3 + 1] + mx * Wc[(HF + t) * 3 + 1] + sum * Wc[(2 * HF + t) * 3 + 1];
        red[2][t] = mean * Wc[t * 3 + 2] + mx * Wc[(HF + t) * 3 + 2] + sum * Wc[(2 * HF + t) * 3 + 2];
    }
    __syncthreads();
    for (int o = 64; o > 0; o >>= 1) {
        if (half == 0 && t < o) {
            red[0][t] += red[0][t + o];
            red[1][t] += red[1][t + o];
            red[2][t] += red[2][t + o];
        }
        __syncthreads();
    }
    if (threadIdx.x < 3) out[g * 3 + threadIdx.x] = red[threadIdx.x][0] + bc[threadIdx.x];
}

extern "C" void kernel_launch(void* const* d_in, const int* in_sizes, int n_in,
                              void* d_out, int out_size, void* d_ws, size_t ws_size,
                              hipStream_t stream) {
    const float* x    = (const float*)d_in[0];
    const int*   ei   = (const int*)d_in[1];
    const int*   batch= (const int*)d_in[2];
    const float* W1   = (const float*)d_in[3];
    const float* b1   = (const float*)d_in[4];
    const float* g1   = (const float*)d_in[5];
    const float* be1  = (const float*)d_in[6];
    const float* W2   = (const float*)d_in[7];
    const float* b2   = (const float*)d_in[8];
    const float* g2   = (const float*)d_in[9];
    const float* be2  = (const float*)d_in[10];
    const float* Wc   = (const float*)d_in[11];
    const float* bc   = (const float*)d_in[12];
    float* out = (float*)d_out;

    const int N = in_sizes[0] / HF;
    const int E = in_sizes[1] / 2;
    const int NG = 256;
    const int* row = ei;
    const int* col = ei + E;
    const int total = N * HF;
    const int nfine = (N + TILE - 1) / TILE;

    // workspace carve-up (256B aligned)
    char* w = (char*)d_ws;
    size_t off = 0;
    auto alloc = [&](size_t bytes) -> void* {
        void* p = w + off;
        off += (bytes + 255) & ~(size_t)255;
        return p;
    };
    int*            cursor   = (int*)alloc((size_t)nfine * 16 * 4);
    int*            cnt_in   = (int*)alloc((size_t)N * 4);
    float*          dinv     = (float*)alloc((size_t)N * 4);
    int*            rowptr   = (int*)alloc(((size_t)N + 1) * 4);
    int*            blocksum = (int*)alloc(256 * 4);
    int*            gstart   = (int*)alloc((NG + 1) * 4);
    int*            srow     = (int*)alloc((size_t)E * 4);
    float*          ssum     = (float*)alloc(HF * 4);   // \ zeroed together
    float*          ssq      = (float*)alloc(HF * 4);   // /
    float*          scale    = (float*)alloc(HF * 4);
    float*          shift    = (float*)alloc(HF * 4);
    unsigned short* A        = (unsigned short*)alloc((size_t)total * 2);  // dinv-scaled xw (bf16)
    float*          B        = (float*)alloc((size_t)total * 4);           // conv out (f32)
    unsigned*       buckets  = (unsigned*)A;  // aliases A (dead before gemm1)

    const int T256 = 256;
    int gridGa   = (N + 15) / 16;
    int gridGemm = (N + 31) / 32;
    int nb       = (N + 255) / 256;
    int gridSort = (E + SORT_CHUNK - 1) / SORT_CHUNK;

    // --- CSR build (once; reused by both convs) ---
    hipMemsetAsync(cursor, 0, (size_t)nfine * 16 * 4, stream);
    bucket_sort<<<gridSort, T256, 0, stream>>>(row, col, buckets, cursor, E, nfine);
    tile_hist_fine<<<nfine, T256, 0, stream>>>(buckets, cursor, cnt_in, N);
    scan_pass1<<<nb, 256, 0, stream>>>(cnt_in, rowptr, blocksum, dinv, N);
    scan_pass23<<<nb, 256, 0, stream>>>(rowptr, blocksum, N, E, nb);
    tile_place_fine<<<nfine, T256, 0, stream>>>(buckets, cursor, rowptr, srow, N);
    graph_bounds<<<2, 129, 0, stream>>>(batch, gstart, N, NG);

    // --- conv1 ---
    gemm_rt<<<gridGemm, T256, 0, stream>>>(x, W1, A, nullptr, nullptr, dinv, N, 0);
    gather_conv<<<gridGa, T256, 0, stream>>>(rowptr, srow, dinv, A, b1, B, N);
    hipMemsetAsync(ssum, 0, 2 * ((HF * 4 + 255) & ~255), stream);
    bn_stats<<<512, 128, 0, stream>>>(B, ssum, ssq, N);
    bn_finalize<<<1, 128, 0, stream>>>(ssum, ssq, g1, be1, scale, shift, N);

    // --- conv2 (BN1+ReLU fused into gemm input load) ---
    gemm_rt<<<gridGemm, T256, 0, stream>>>(B, W2, A, scale, shift, dinv, N, 1);
    gather_conv<<<gridGa, T256, 0, stream>>>(rowptr, srow, dinv, A, b2, B, N);
    hipMemsetAsync(ssum, 0, 2 * ((HF * 4 + 255) & ~255), stream);
    bn_stats<<<512, 128, 0, stream>>>(B, ssum, ssq, N);
    bn_finalize<<<1, 128, 0, stream>>>(ssum, ssq, g2, be2, scale, shift, N);

    // --- fused BN2+ReLU + pooling + classifier ---
    pool_classify<<<NG, 256, 0, stream>>>(B, gstart, scale, shift, Wc, bc, out);
}

// Round 12
// 349.006 us; speedup vs baseline: 2.0173x; 1.0060x over previous
//
#include <hip/hip_runtime.h>

#define HF 128       // feature width (F == H == 128)
#define TILE 128     // cols per fine bucket
#define CAP2 6144    // entries per fine bucket (mean ~4096 + slack)
#define NFINE_MAX 512
#define SORT_CHUNK 4096

__device__ __forceinline__ unsigned short f2bf(float f) {
    unsigned u = __float_as_uint(f);
    unsigned rounding = 0x7FFF + ((u >> 16) & 1);  // round-to-nearest-even
    return (unsigned short)((u + rounding) >> 16);
}

// ---------- single-pass block counting sort into fine 128-col buckets ----------
__global__ __launch_bounds__(256) void bucket_sort(const int* __restrict__ row,
                                                   const int* __restrict__ col,
                                                   unsigned* __restrict__ buckets,
                                                   int* __restrict__ cursor,  // stride 16 ints
                                                   int E, int nfine) {
    __shared__ int hist[NFINE_MAX], lbase[NFINE_MAX], gbase[NFINE_MAX], lofs[NFINE_MAX];
    __shared__ int s[512];
    __shared__ unsigned staged[SORT_CHUNK];
    __shared__ unsigned short sbkt[SORT_CHUNK];
    int t = threadIdx.x;
    for (int i = t; i < NFINE_MAX; i += 256) { hist[i] = 0; lofs[i] = 0; }
    __syncthreads();
    int e0 = blockIdx.x * SORT_CHUNK;
    int n = min(SORT_CHUNK, E - e0);
    for (int i = t; i < n; i += 256) {
        int c = col[e0 + i];
        atomicAdd(&hist[c >> 7], 1);
    }
    __syncthreads();
    s[t] = hist[t];
    s[t + 256] = hist[t + 256];
    for (int o = 1; o < 512; o <<= 1) {
        __syncthreads();
        int idx = (t + 1) * (o << 1) - 1;
        if (idx < 512) s[idx] += s[idx - o];
    }
    __syncthreads();
    if (t == 0) s[511] = 0;
    for (int o = 256; o >= 1; o >>= 1) {
        __syncthreads();
        int idx = (t + 1) * (o << 1) - 1;
        if (idx < 512) { int tmp = s[idx - o]; s[idx - o] = s[idx]; s[idx] += tmp; }
    }
    __syncthreads();
    lbase[t] = s[t];
    lbase[t + 256] = s[t + 256];
    for (int b = t; b < nfine; b += 256) {
        int cnt = hist[b];
        gbase[b] = cnt ? atomicAdd(&cursor[b * 16], cnt) : 0;
    }
    __syncthreads();
    for (int i = t; i < n; i += 256) {
        int c = col[e0 + i];
        int r = row[e0 + i];
        int b = c >> 7;
        int pos = lbase[b] + atomicAdd(&lofs[b], 1);
        staged[pos] = ((unsigned)(c & 127) << 17) | (unsigned)r;
        sbkt[pos] = (unsigned short)b;
    }
    __syncthreads();
    for (int i = t; i < n; i += 256) {
        int b = sbkt[i];
        int pos = gbase[b] + (i - lbase[b]);
        if (pos < CAP2) buckets[(size_t)b * CAP2 + pos] = staged[i];
    }
}

// ---------- bucket-size scan: cursor -> bucket_base; also rowptr[N] = total ----------
__global__ __launch_bounds__(512) void bucket_scan(const int* __restrict__ cursor,
                                                   int* __restrict__ bucket_base,
                                                   int* __restrict__ rowptr,
                                                   int nfine, int N) {
    __shared__ int s[512];
    int t = threadIdx.x;
    int v = (t < nfine) ? min(cursor[t * 16], CAP2) : 0;
    s[t] = v;
    __syncthreads();
    for (int o = 1; o < 512; o <<= 1) {
        int tv = (t >= o) ? s[t - o] : 0;
        __syncthreads();
        s[t] += tv;
        __syncthreads();
    }
    if (t < nfine) bucket_base[t] = s[t] - v;  // exclusive
    if (t == 511) rowptr[N] = s[511];          // total == E (absent overflow)
}

// ---------- fused per-bucket: hist + local scan -> rowptr/dinv; place -> srow ----------
__global__ __launch_bounds__(256) void tile_place2(const unsigned* __restrict__ buckets,
                                                   const int* __restrict__ cursor,
                                                   const int* __restrict__ bucket_base,
                                                   int* __restrict__ rowptr,
                                                   float* __restrict__ dinv,
                                                   int* __restrict__ srow, int N) {
    int b = blockIdx.x;
    __shared__ int h[TILE], loc[TILE], cur[TILE];
    __shared__ int stage[CAP2];
    int t = threadIdx.x;
    if (t < TILE) h[t] = 0;
    __syncthreads();
    int sz = min(cursor[b * 16], CAP2);
    const unsigned* bk = buckets + (size_t)b * CAP2;
    for (int i = t; i < sz; i += 256) atomicAdd(&h[bk[i] >> 17], 1);
    __syncthreads();
    if (t < TILE) loc[t] = h[t];
    __syncthreads();
    for (int o = 1; o < TILE; o <<= 1) {
        int v = (t < TILE && t >= o) ? loc[t - o] : 0;
        __syncthreads();
        if (t < TILE) loc[t] += v;
        __syncthreads();
    }
    int base = bucket_base[b];
    if (t < TILE) {
        int c = b * TILE + t;
        int excl = loc[t] - h[t];
        if (c < N) {
            rowptr[c] = base + excl;
            dinv[c] = rsqrtf((float)h[t] + 1.0f);
        }
        cur[t] = excl;
    }
    __syncthreads();
    for (int i = t; i < sz; i += 256) {
        unsigned p = bk[i];
        int pos = atomicAdd(&cur[p >> 17], 1);
        if (pos < CAP2) stage[pos] = (int)(p & 0x1FFFFu);
    }
    __syncthreads();
    for (int i = t; i < sz; i += 256) srow[base + i] = stage[i];
}

// ---------- register-tiled GEMM: 64-row x 128-col block, 8x4 per thread ----------
// Y[N,128](bf16) = rowscale[r] * (BNReLU?(X[N,128]) @ W[128,128])
// Per k-step/thread: 2 ds_read_b128 + 1 global dwordx4 (W, L2-hot) + 32 FMA.
__global__ __launch_bounds__(256) void gemm_rt(const float* __restrict__ X,
                                               const float* __restrict__ W,
                                               unsigned short* __restrict__ Y,
                                               const float* __restrict__ scale,
                                               const float* __restrict__ shift,
                                               const float* __restrict__ rowscale,
                                               int N, int applyBN) {
    __shared__ float xst[HF][68];  // transposed X tile, 272B row stride (16B-aligned)
    int t = threadIdx.x;
    int row0 = blockIdx.x * 64;
    {
        int f = t & 127;
        float sc = applyBN ? scale[f] : 1.0f;
        float sh = applyBN ? shift[f] : 0.0f;
        for (int r = (t >> 7); r < 64; r += 2) {
            int rr = row0 + r;
            float v = (rr < N) ? X[(size_t)rr * HF + f] : 0.0f;
            if (applyBN) v = fmaxf(v * sc + sh, 0.0f);
            xst[f][r] = v;
        }
    }
    __syncthreads();
    int cg = t & 31;   // cols 4*cg..+3
    int rg = t >> 5;   // rows rg*8..+7
    int r0 = rg * 8;
    float acc[8][4] = {};
    const float4* Wv = reinterpret_cast<const float4*>(W);
    #pragma unroll 2
    for (int f = 0; f < HF; ++f) {
        float4 w = Wv[f * 32 + cg];
        float4 x0 = *reinterpret_cast<const float4*>(&xst[f][r0]);
        float4 x1 = *reinterpret_cast<const float4*>(&xst[f][r0 + 4]);
        float xr[8] = {x0.x, x0.y, x0.z, x0.w, x1.x, x1.y, x1.z, x1.w};
        #pragma unroll
        for (int i = 0; i < 8; ++i) {
            acc[i][0] += xr[i] * w.x;
            acc[i][1] += xr[i] * w.y;
            acc[i][2] += xr[i] * w.z;
            acc[i][3] += xr[i] * w.w;
        }
    }
    #pragma unroll
    for (int i = 0; i < 8; ++i) {
        int rr = row0 + r0 + i;
        if (rr < N) {
            float rs = rowscale[rr];
            ushort4 o;
            o.x = f2bf(acc[i][0] * rs);
            o.y = f2bf(acc[i][1] * rs);
            o.z = f2bf(acc[i][2] * rs);
            o.w = f2bf(acc[i][3] * rs);
            *reinterpret_cast<ushort4*>(&Y[(size_t)rr * HF + cg * 4]) = o;
        }
    }
}

// ---------- gather-side conv on pre-scaled bf16 XWs (4-deep edge unroll) ----------
__global__ __launch_bounds__(256) void gather_conv(const int* __restrict__ rowptr,
                                                   const int* __restrict__ srow,
                                                   const float* __restrict__ dinv,
                                                   const unsigned short* __restrict__ XW,
                                                   const float* __restrict__ b,
                                                   float* __restrict__ OUT, int N) {
    int c = blockIdx.x * 16 + (threadIdx.x >> 4);
    int j = threadIdx.x & 15;  // 8 features per lane
    if (c >= N) return;
    int e = rowptr[c], end = rowptr[c + 1];
    float acc[8] = {0.f, 0.f, 0.f, 0.f, 0.f, 0.f, 0.f, 0.f};
    const unsigned M = 0xffff0000u;
    for (; e + 3 < end; e += 4) {
        int r0 = srow[e], r1 = srow[e + 1], r2 = srow[e + 2], r3 = srow[e + 3];
        uint4 u0 = *reinterpret_cast<const uint4*>(XW + (size_t)r0 * HF + j * 8);
        uint4 u1 = *reinterpret_cast<const uint4*>(XW + (size_t)r1 * HF + j * 8);
        uint4 u2 = *reinterpret_cast<const uint4*>(XW + (size_t)r2 * HF + j * 8);
        uint4 u3 = *reinterpret_cast<const uint4*>(XW + (size_t)r3 * HF + j * 8);
        acc[0] += (__uint_as_float(u0.x << 16) + __uint_as_float(u1.x << 16))
                + (__uint_as_float(u2.x << 16) + __uint_as_float(u3.x << 16));
        acc[1] += (__uint_as_float(u0.x & M) + __uint_as_float(u1.x & M))
                + (__uint_as_float(u2.x & M) + __uint_as_float(u3.x & M));
        acc[2] += (__uint_as_float(u0.y << 16) + __uint_as_float(u1.y << 16))
                + (__uint_as_float(u2.y << 16) + __uint_as_float(u3.y << 16));
        acc[3] += (__uint_as_float(u0.y & M) + __uint_as_float(u1.y & M))
                + (__uint_as_float(u2.y & M) + __uint_as_float(u3.y & M));
        acc[4] += (__uint_as_float(u0.z << 16) + __uint_as_float(u1.z << 16))
                + (__uint_as_float(u2.z << 16) + __uint_as_float(u3.z << 16));
        acc[5] += (__uint_as_float(u0.z & M) + __uint_as_float(u1.z & M))
                + (__uint_as_float(u2.z & M) + __uint_as_float(u3.z & M));
        acc[6] += (__uint_as_float(u0.w << 16) + __uint_as_float(u1.w << 16))
                + (__uint_as_float(u2.w << 16) + __uint_as_float(u3.w << 16));
        acc[7] += (__uint_as_float(u0.w & M) + __uint_as_float(u1.w & M))
                + (__uint_as_float(u2.w & M) + __uint_as_float(u3.w & M));
    }
    for (; e < end; ++e) {
        int r0 = srow[e];
        uint4 u0 = *reinterpret_cast<const uint4*>(XW + (size_t)r0 * HF + j * 8);
        acc[0] += __uint_as_float(u0.x << 16);
        acc[1] += __uint_as_float(u0.x & M);
        acc[2] += __uint_as_float(u0.y << 16);
        acc[3] += __uint_as_float(u0.y & M);
        acc[4] += __uint_as_float(u0.z << 16);
        acc[5] += __uint_as_float(u0.z & M);
        acc[6] += __uint_as_float(u0.w << 16);
        acc[7] += __uint_as_float(u0.w & M);
    }
    float dc = dinv[c];
    uint4 xv = *reinterpret_cast<const uint4*>(XW + (size_t)c * HF + j * 8);
    acc[0] += __uint_as_float(xv.x << 16);
    acc[1] += __uint_as_float(xv.x & M);
    acc[2] += __uint_as_float(xv.y << 16);
    acc[3] += __uint_as_float(xv.y & M);
    acc[4] += __uint_as_float(xv.z << 16);
    acc[5] += __uint_as_float(xv.z & M);
    acc[6] += __uint_as_float(xv.w << 16);
    acc[7] += __uint_as_float(xv.w & M);
    float4 b0 = *reinterpret_cast<const float4*>(b + j * 8);
    float4 b1 = *reinterpret_cast<const float4*>(b + j * 8 + 4);
    float4 o0, o1;
    o0.x = dc * acc[0] + b0.x;
    o0.y = dc * acc[1] + b0.y;
    o0.z = dc * acc[2] + b0.z;
    o0.w = dc * acc[3] + b0.w;
    o1.x = dc * acc[4] + b1.x;
    o1.y = dc * acc[5] + b1.y;
    o1.z = dc * acc[6] + b1.z;
    o1.w = dc * acc[7] + b1.w;
    float* op = OUT + (size_t)c * HF + j * 8;
    *reinterpret_cast<float4*>(op) = o0;
    *reinterpret_cast<float4*>(op + 4) = o1;
}

// ---------- BN stats ----------
__global__ __launch_bounds__(128) void bn_stats(const float* __restrict__ Y,
                                                float* __restrict__ ssum,
                                                float* __restrict__ ssq, int N) {
    int t = threadIdx.x;
    float s = 0.f, sq = 0.f;
    for (int n = blockIdx.x; n < N; n += gridDim.x) {
        float v = Y[(size_t)n * HF + t];
        s += v;
        sq += v * v;
    }
    atomicAdd(&ssum[t], s);
    atomicAdd(&ssq[t], sq);
}

__global__ __launch_bounds__(128) void bn_finalize(const float* __restrict__ ssum,
                                                   const float* __restrict__ ssq,
                                                   const float* __restrict__ gamma,
                                                   const float* __restrict__ beta,
                                                   float* __restrict__ scale,
                                                   float* __restrict__ shift, int N) {
    int t = threadIdx.x;
    float invn = 1.0f / (float)N;
    float mu = ssum[t] * invn;
    float var = ssq[t] * invn - mu * mu;
    float sc = gamma[t] * rsqrtf(var + 1e-5f);
    scale[t] = sc;
    shift[t] = beta[t] - mu * sc;
}

// ---------- graph boundaries (batch sorted) ----------
__global__ void graph_bounds(const int* __restrict__ batch, int* __restrict__ gstart,
                             int N, int NG) {
    int g = blockIdx.x * blockDim.x + threadIdx.x;
    if (g > NG) return;
    int lo = 0, hi = N;
    while (lo < hi) {
        int mid = (lo + hi) >> 1;
        if (batch[mid] < g) lo = mid + 1; else hi = mid;
    }
    gstart[g] = lo;
}

// ---------- fused BN2+ReLU + mean/max/sum pool + classifier ----------
__global__ __launch_bounds__(256) void pool_classify(const float* __restrict__ B,
                                                     const int* __restrict__ gstart,
                                                     const float* __restrict__ scale,
                                                     const float* __restrict__ shift,
                                                     const float* __restrict__ Wc,
                                                     const float* __restrict__ bc,
                                                     float* __restrict__ out) {
    int g = blockIdx.x;
    int t = threadIdx.x & 127;
    int half = threadIdx.x >> 7;
    int s0 = gstart[g], s1 = gstart[g + 1];
    float sc = scale[t], sh = shift[t];
    float sum = 0.f, mx = 0.f;  // 0-init == empty-graph guard (post-ReLU v >= 0)
    for (int n = s0 + half; n < s1; n += 2) {
        float v = fmaxf(B[(size_t)n * HF + t] * sc + sh, 0.0f);
        sum += v;
        mx = fmaxf(mx, v);
    }
    __shared__ float shsum[2][HF], shmax[2][HF];
    __shared__ float red[3][HF];
    shsum[half][t] = sum;
    shmax[half][t] = mx;
    __syncthreads();
    if (half == 0) {
        sum += shsum[1][t];
        mx = fmaxf(mx, shmax[1][t]);
        float cntf = (float)(s1 - s0);
        float mean = sum / fmaxf(cntf, 1.0f);
        red[0][t] = mean * Wc[t * 3 + 0] + mx * Wc[(HF + t) * 3 + 0] + sum * Wc[(2 * HF + t) * 3 + 0];
        red[1][t] = mean * Wc[t * 3 + 1] + mx * Wc[(HF + t) * 3 + 1] + sum * Wc[(2 * HF + t) * 3 + 1];
        red[2][t] = mean * Wc[t * 3 + 2] + mx * Wc[(HF + t) * 3 + 2] + sum * Wc[(2 * HF + t) * 3 + 2];
    }
    __syncthreads();
    for (int o = 64; o > 0; o >>= 1) {
        if (half == 0 && t < o) {
            red[0][t] += red[0][t + o];
            red[1][t] += red[1][t + o];
            red[2][t] += red[2][t + o];
        }
        __syncthreads();
    }
    if (threadIdx.x < 3) out[g * 3 + threadIdx.x] = red[threadIdx.x][0] + bc[threadIdx.x];
}

extern "C" void kernel_launch(void* const* d_in, const int* in_sizes, int n_in,
                              void* d_out, int out_size, void* d_ws, size_t ws_size,
                              hipStream_t stream) {
    const float* x    = (const float*)d_in[0];
    const int*   ei   = (const int*)d_in[1];
    const int*   batch= (const int*)d_in[2];
    const float* W1   = (const float*)d_in[3];
    const float* b1   = (const float*)d_in[4];
    const float* g1   = (const float*)d_in[5];
    const float* be1  = (const float*)d_in[6];
    const float* W2   = (const float*)d_in[7];
    const float* b2   = (const float*)d_in[8];
    const float* g2   = (const float*)d_in[9];
    const float* be2  = (const float*)d_in[10];
    const float* Wc   = (const float*)d_in[11];
    const float* bc   = (const float*)d_in[12];
    float* out = (float*)d_out;

    const int N = in_sizes[0] / HF;
    const int E = in_sizes[1] / 2;
    const int NG = 256;
    const int* row = ei;
    const int* col = ei + E;
    const int total = N * HF;
    const int nfine = (N + TILE - 1) / TILE;  // <= 512

    // workspace carve-up (256B aligned)
    char* w = (char*)d_ws;
    size_t off = 0;
    auto alloc = [&](size_t bytes) -> void* {
        void* p = w + off;
        off += (bytes + 255) & ~(size_t)255;
        return p;
    };
    int*            cursor    = (int*)alloc((size_t)nfine * 16 * 4);
    float*          dinv      = (float*)alloc((size_t)N * 4);
    int*            rowptr    = (int*)alloc(((size_t)N + 1) * 4);
    int*            bucket_b  = (int*)alloc(NFINE_MAX * 4);
    int*            gstart    = (int*)alloc((NG + 1) * 4);
    int*            srow      = (int*)alloc((size_t)E * 4);
    float*          ssum      = (float*)alloc(HF * 4);   // \ zeroed together
    float*          ssq       = (float*)alloc(HF * 4);   // /
    float*          scale     = (float*)alloc(HF * 4);
    float*          shift     = (float*)alloc(HF * 4);
    unsigned short* A         = (unsigned short*)alloc((size_t)total * 2);  // dinv-scaled xw (bf16)
    float*          B         = (float*)alloc((size_t)total * 4);           // conv out (f32)
    unsigned*       buckets   = (unsigned*)A;  // aliases A (dead before gemm1)

    const int T256 = 256;
    int gridGa   = (N + 15) / 16;
    int gridGemm = (N + 63) / 64;
    int gridSort = (E + SORT_CHUNK - 1) / SORT_CHUNK;

    // --- CSR build (once; reused by both convs) ---
    hipMemsetAsync(cursor, 0, (size_t)nfine * 16 * 4, stream);
    bucket_sort<<<gridSort, T256, 0, stream>>>(row, col, buckets, cursor, E, nfine);
    bucket_scan<<<1, 512, 0, stream>>>(cursor, bucket_b, rowptr, nfine, N);
    tile_place2<<<nfine, T256, 0, stream>>>(buckets, cursor, bucket_b, rowptr, dinv, srow, N);
    graph_bounds<<<2, 129, 0, stream>>>(batch, gstart, N, NG);

    // --- conv1 (GEMM output rows pre-scaled by dinv) ---
    gemm_rt<<<gridGemm, T256, 0, stream>>>(x, W1, A, nullptr, nullptr, dinv, N, 0);
    gather_conv<<<gridGa, T256, 0, stream>>>(rowptr, srow, dinv, A, b1, B, N);
    hipMemsetAsync(ssum, 0, 2 * ((HF * 4 + 255) & ~255), stream);
    bn_stats<<<512, 128, 0, stream>>>(B, ssum, ssq, N);
    bn_finalize<<<1, 128, 0, stream>>>(ssum, ssq, g1, be1, scale, shift, N);

    // --- conv2 (BN1+ReLU fused into gemm input load) ---
    gemm_rt<<<gridGemm, T256, 0, stream>>>(B, W2, A, scale, shift, dinv, N, 1);
    gather_conv<<<gridGa, T256, 0, stream>>>(rowptr, srow, dinv, A, b2, B, N);
    hipMemsetAsync(ssum, 0, 2 * ((HF * 4 + 255) & ~255), stream);
    bn_stats<<<512, 128, 0, stream>>>(B, ssum, ssq, N);
    bn_finalize<<<1, 128, 0, stream>>>(ssum, ssq, g2, be2, scale, shift, N);

    // --- fused BN2+ReLU + pooling + classifier ---
    pool_classify<<<NG, 256, 0, stream>>>(B, gstart, scale, shift, Wc, bc, out);
}

// Round 13
// 338.206 us; speedup vs baseline: 2.0817x; 1.0319x over previous
//
#include <hip/hip_runtime.h>

#define HF 128       // feature width (F == H == 128)
#define TILE 128     // cols per fine bucket
#define CAP2 6144    // entries per fine bucket (mean ~4096 + slack)
#define NFINE_MAX 512
#define SORT_CHUNK 4096
#define BN_EPS 1e-5f

__device__ __forceinline__ unsigned short f2bf(float f) {
    unsigned u = __float_as_uint(f);
    unsigned rounding = 0x7FFF + ((u >> 16) & 1);  // round-to-nearest-even
    return (unsigned short)((u + rounding) >> 16);
}

// ---------- single-pass block counting sort into fine 128-col buckets ----------
__global__ __launch_bounds__(256) void bucket_sort(const int* __restrict__ row,
                                                   const int* __restrict__ col,
                                                   unsigned* __restrict__ buckets,
                                                   int* __restrict__ cursor,  // stride 16 ints
                                                   int E, int nfine) {
    __shared__ int hist[NFINE_MAX], lbase[NFINE_MAX], gbase[NFINE_MAX], lofs[NFINE_MAX];
    __shared__ int s[512];
    __shared__ unsigned staged[SORT_CHUNK];
    __shared__ unsigned short sbkt[SORT_CHUNK];
    int t = threadIdx.x;
    for (int i = t; i < NFINE_MAX; i += 256) { hist[i] = 0; lofs[i] = 0; }
    __syncthreads();
    int e0 = blockIdx.x * SORT_CHUNK;
    int n = min(SORT_CHUNK, E - e0);
    for (int i = t; i < n; i += 256) {
        int c = col[e0 + i];
        atomicAdd(&hist[c >> 7], 1);
    }
    __syncthreads();
    s[t] = hist[t];
    s[t + 256] = hist[t + 256];
    for (int o = 1; o < 512; o <<= 1) {
        __syncthreads();
        int idx = (t + 1) * (o << 1) - 1;
        if (idx < 512) s[idx] += s[idx - o];
    }
    __syncthreads();
    if (t == 0) s[511] = 0;
    for (int o = 256; o >= 1; o >>= 1) {
        __syncthreads();
        int idx = (t + 1) * (o << 1) - 1;
        if (idx < 512) { int tmp = s[idx - o]; s[idx - o] = s[idx]; s[idx] += tmp; }
    }
    __syncthreads();
    lbase[t] = s[t];
    lbase[t + 256] = s[t + 256];
    for (int b = t; b < nfine; b += 256) {
        int cnt = hist[b];
        gbase[b] = cnt ? atomicAdd(&cursor[b * 16], cnt) : 0;
    }
    __syncthreads();
    for (int i = t; i < n; i += 256) {
        int c = col[e0 + i];
        int r = row[e0 + i];
        int b = c >> 7;
        int pos = lbase[b] + atomicAdd(&lofs[b], 1);
        staged[pos] = ((unsigned)(c & 127) << 17) | (unsigned)r;
        sbkt[pos] = (unsigned short)b;
    }
    __syncthreads();
    for (int i = t; i < n; i += 256) {
        int b = sbkt[i];
        int pos = gbase[b] + (i - lbase[b]);
        if (pos < CAP2) buckets[(size_t)b * CAP2 + pos] = staged[i];
    }
}

// ---------- fused per-bucket: own prefix + hist + scan -> rowptr/dinv; place -> srow ----------
// Also folds graph_bounds (blocks 0-1) and rowptr[N]=E (last block).
__global__ __launch_bounds__(256) void tile_place2(const unsigned* __restrict__ buckets,
                                                   const int* __restrict__ cursor,
                                                   int* __restrict__ rowptr,
                                                   float* __restrict__ dinv,
                                                   int* __restrict__ srow,
                                                   const int* __restrict__ batch,
                                                   int* __restrict__ gstart,
                                                   int N, int NG, int nfine) {
    int b = blockIdx.x;
    int t = threadIdx.x;
    // folded graph_bounds: gstart[g] = lower_bound(batch, g), g in [0, NG]
    if (b < 2 && t < 129) {
        int g = b * 129 + t;
        if (g <= NG) {
            int lo = 0, hi = N;
            while (lo < hi) {
                int mid = (lo + hi) >> 1;
                if (batch[mid] < g) lo = mid + 1; else hi = mid;
            }
            gstart[g] = lo;
        }
    }
    __shared__ int h[TILE], loc[TILE], cur[TILE];
    __shared__ int red[256];
    __shared__ int stage[CAP2];
    // own exclusive prefix over buckets [0, b)
    int part = 0;
    for (int i = t; i < b; i += 256) part += min(cursor[i * 16], CAP2);
    red[t] = part;
    if (t < TILE) h[t] = 0;
    __syncthreads();
    for (int o = 128; o > 0; o >>= 1) {
        if (t < o) red[t] += red[t + o];
        __syncthreads();
    }
    int base = red[0];
    int sz = min(cursor[b * 16], CAP2);
    const unsigned* bk = buckets + (size_t)b * CAP2;
    for (int i = t; i < sz; i += 256) atomicAdd(&h[bk[i] >> 17], 1);
    __syncthreads();
    if (t < TILE) loc[t] = h[t];
    __syncthreads();
    for (int o = 1; o < TILE; o <<= 1) {
        int v = (t < TILE && t >= o) ? loc[t - o] : 0;
        __syncthreads();
        if (t < TILE) loc[t] += v;
        __syncthreads();
    }
    if (t < TILE) {
        int c = b * TILE + t;
        int excl = loc[t] - h[t];
        if (c < N) {
            rowptr[c] = base + excl;
            dinv[c] = rsqrtf((float)h[t] + 1.0f);
        }
        cur[t] = excl;
    }
    if (b == nfine - 1 && t == 0) rowptr[N] = base + sz;
    __syncthreads();
    for (int i = t; i < sz; i += 256) {
        unsigned p = bk[i];
        int pos = atomicAdd(&cur[p >> 17], 1);
        if (pos < CAP2) stage[pos] = (int)(p & 0x1FFFFu);
    }
    __syncthreads();
    for (int i = t; i < sz; i += 256) srow[base + i] = stage[i];
}

// ---------- register-tiled GEMM: 64-row x 128-col block, 8x4 per thread ----------
// Y = rowscale[r] * (BNReLU?(X) @ W). BN scale/shift computed inline from
// ssum_in/ssq_in (stats of X) -- bn_finalize folded in. Block 0 also zeroes
// the NEXT stage's stats buffers (replaces a memset; runs before its bn_stats).
__global__ __launch_bounds__(256) void gemm_rt(const float* __restrict__ X,
                                               const float* __restrict__ W,
                                               unsigned short* __restrict__ Y,
                                               const float* __restrict__ ssum_in,
                                               const float* __restrict__ ssq_in,
                                               const float* __restrict__ gamma,
                                               const float* __restrict__ beta,
                                               const float* __restrict__ rowscale,
                                               float* __restrict__ ssum_zero,
                                               float* __restrict__ ssq_zero,
                                               int N, int applyBN) {
    __shared__ float xst[HF][68];  // transposed X tile, 272B row stride
    int t = threadIdx.x;
    int row0 = blockIdx.x * 64;
    if (blockIdx.x == 0 && t < HF) { ssum_zero[t] = 0.f; ssq_zero[t] = 0.f; }
    {
        int f = t & 127;
        float sc = 1.0f, sh = 0.0f;
        if (applyBN) {
            float invn = 1.0f / (float)N;
            float mu = ssum_in[f] * invn;
            float var = ssq_in[f] * invn - mu * mu;
            sc = gamma[f] * rsqrtf(var + BN_EPS);
            sh = beta[f] - mu * sc;
        }
        for (int r = (t >> 7); r < 64; r += 2) {
            int rr = row0 + r;
            float v = (rr < N) ? X[(size_t)rr * HF + f] : 0.0f;
            if (applyBN) v = fmaxf(v * sc + sh, 0.0f);
            xst[f][r] = v;
        }
    }
    __syncthreads();
    int cg = t & 31;   // cols 4*cg..+3
    int rg = t >> 5;   // rows rg*8..+7
    int r0 = rg * 8;
    float acc[8][4] = {};
    const float4* Wv = reinterpret_cast<const float4*>(W);
    #pragma unroll 2
    for (int f = 0; f < HF; ++f) {
        float4 w = Wv[f * 32 + cg];
        float4 x0 = *reinterpret_cast<const float4*>(&xst[f][r0]);
        float4 x1 = *reinterpret_cast<const float4*>(&xst[f][r0 + 4]);
        float xr[8] = {x0.x, x0.y, x0.z, x0.w, x1.x, x1.y, x1.z, x1.w};
        #pragma unroll
        for (int i = 0; i < 8; ++i) {
            acc[i][0] += xr[i] * w.x;
            acc[i][1] += xr[i] * w.y;
            acc[i][2] += xr[i] * w.z;
            acc[i][3] += xr[i] * w.w;
        }
    }
    #pragma unroll
    for (int i = 0; i < 8; ++i) {
        int rr = row0 + r0 + i;
        if (rr < N) {
            float rs = rowscale[rr];
            ushort4 o;
            o.x = f2bf(acc[i][0] * rs);
            o.y = f2bf(acc[i][1] * rs);
            o.z = f2bf(acc[i][2] * rs);
            o.w = f2bf(acc[i][3] * rs);
            *reinterpret_cast<ushort4*>(&Y[(size_t)rr * HF + cg * 4]) = o;
        }
    }
}

// ---------- gather-side conv on pre-scaled bf16 XWs (4-deep edge unroll) ----------
__global__ __launch_bounds__(256) void gather_conv(const int* __restrict__ rowptr,
                                                   const int* __restrict__ srow,
                                                   const float* __restrict__ dinv,
                                                   const unsigned short* __restrict__ XW,
                                                   const float* __restrict__ b,
                                                   float* __restrict__ OUT, int N) {
    int c = blockIdx.x * 16 + (threadIdx.x >> 4);
    int j = threadIdx.x & 15;  // 8 features per lane
    if (c >= N) return;
    int e = rowptr[c], end = rowptr[c + 1];
    float acc[8] = {0.f, 0.f, 0.f, 0.f, 0.f, 0.f, 0.f, 0.f};
    const unsigned M = 0xffff0000u;
    for (; e + 3 < end; e += 4) {
        int r0 = srow[e], r1 = srow[e + 1], r2 = srow[e + 2], r3 = srow[e + 3];
        uint4 u0 = *reinterpret_cast<const uint4*>(XW + (size_t)r0 * HF + j * 8);
        uint4 u1 = *reinterpret_cast<const uint4*>(XW + (size_t)r1 * HF + j * 8);
        uint4 u2 = *reinterpret_cast<const uint4*>(XW + (size_t)r2 * HF + j * 8);
        uint4 u3 = *reinterpret_cast<const uint4*>(XW + (size_t)r3 * HF + j * 8);
        acc[0] += (__uint_as_float(u0.x << 16) + __uint_as_float(u1.x << 16))
                + (__uint_as_float(u2.x << 16) + __uint_as_float(u3.x << 16));
        acc[1] += (__uint_as_float(u0.x & M) + __uint_as_float(u1.x & M))
                + (__uint_as_float(u2.x & M) + __uint_as_float(u3.x & M));
        acc[2] += (__uint_as_float(u0.y << 16) + __uint_as_float(u1.y << 16))
                + (__uint_as_float(u2.y << 16) + __uint_as_float(u3.y << 16));
        acc[3] += (__uint_as_float(u0.y & M) + __uint_as_float(u1.y & M))
                + (__uint_as_float(u2.y & M) + __uint_as_float(u3.y & M));
        acc[4] += (__uint_as_float(u0.z << 16) + __uint_as_float(u1.z << 16))
                + (__uint_as_float(u2.z << 16) + __uint_as_float(u3.z << 16));
        acc[5] += (__uint_as_float(u0.z & M) + __uint_as_float(u1.z & M))
                + (__uint_as_float(u2.z & M) + __uint_as_float(u3.z & M));
        acc[6] += (__uint_as_float(u0.w << 16) + __uint_as_float(u1.w << 16))
                + (__uint_as_float(u2.w << 16) + __uint_as_float(u3.w << 16));
        acc[7] += (__uint_as_float(u0.w & M) + __uint_as_float(u1.w & M))
                + (__uint_as_float(u2.w & M) + __uint_as_float(u3.w & M));
    }
    for (; e < end; ++e) {
        int r0 = srow[e];
        uint4 u0 = *reinterpret_cast<const uint4*>(XW + (size_t)r0 * HF + j * 8);
        acc[0] += __uint_as_float(u0.x << 16);
        acc[1] += __uint_as_float(u0.x & M);
        acc[2] += __uint_as_float(u0.y << 16);
        acc[3] += __uint_as_float(u0.y & M);
        acc[4] += __uint_as_float(u0.z << 16);
        acc[5] += __uint_as_float(u0.z & M);
        acc[6] += __uint_as_float(u0.w << 16);
        acc[7] += __uint_as_float(u0.w & M);
    }
    float dc = dinv[c];
    uint4 xv = *reinterpret_cast<const uint4*>(XW + (size_t)c * HF + j * 8);
    acc[0] += __uint_as_float(xv.x << 16);
    acc[1] += __uint_as_float(xv.x & M);
    acc[2] += __uint_as_float(xv.y << 16);
    acc[3] += __uint_as_float(xv.y & M);
    acc[4] += __uint_as_float(xv.z << 16);
    acc[5] += __uint_as_float(xv.z & M);
    acc[6] += __uint_as_float(xv.w << 16);
    acc[7] += __uint_as_float(xv.w & M);
    float4 b0 = *reinterpret_cast<const float4*>(b + j * 8);
    float4 b1 = *reinterpret_cast<const float4*>(b + j * 8 + 4);
    float4 o0, o1;
    o0.x = dc * acc[0] + b0.x;
    o0.y = dc * acc[1] + b0.y;
    o0.z = dc * acc[2] + b0.z;
    o0.w = dc * acc[3] + b0.w;
    o1.x = dc * acc[4] + b1.x;
    o1.y = dc * acc[5] + b1.y;
    o1.z = dc * acc[6] + b1.z;
    o1.w = dc * acc[7] + b1.w;
    float* op = OUT + (size_t)c * HF + j * 8;
    *reinterpret_cast<float4*>(op) = o0;
    *reinterpret_cast<float4*>(op + 4) = o1;
}

// ---------- BN stats (into pre-zeroed buffers) ----------
__global__ __launch_bounds__(128) void bn_stats(const float* __restrict__ Y,
                                                float* __restrict__ ssum,
                                                float* __restrict__ ssq, int N) {
    int t = threadIdx.x;
    float s = 0.f, sq = 0.f;
    for (int n = blockIdx.x; n < N; n += gridDim.x) {
        float v = Y[(size_t)n * HF + t];
        s += v;
        sq += v * v;
    }
    atomicAdd(&ssum[t], s);
    atomicAdd(&ssq[t], sq);
}

// ---------- fused BN2(inline finalize)+ReLU + mean/max/sum pool + classifier ----------
__global__ __launch_bounds__(256) void pool_classify(const float* __restrict__ B,
                                                     const int* __restrict__ gstart,
                                                     const float* __restrict__ ssum,
                                                     const float* __restrict__ ssq,
                                                     const float* __restrict__ gamma,
                                                     const float* __restrict__ beta,
                                                     const float* __restrict__ Wc,
                                                     const float* __restrict__ bc,
                                                     float* __restrict__ out, int N) {
    int g = blockIdx.x;
    int t = threadIdx.x & 127;
    int half = threadIdx.x >> 7;
    int s0 = gstart[g], s1 = gstart[g + 1];
    float invn = 1.0f / (float)N;
    float mu = ssum[t] * invn;
    float var = ssq[t] * invn - mu * mu;
    float sc = gamma[t] * rsqrtf(var + BN_EPS);
    float sh = beta[t] - mu * sc;
    float sum = 0.f, mx = 0.f;  // 0-init == empty-graph guard (post-ReLU v >= 0)
    for (int n = s0 + half; n < s1; n += 2) {
        float v = fmaxf(B[(size_t)n * HF + t] * sc + sh, 0.0f);
        sum += v;
        mx = fmaxf(mx, v);
    }
    __shared__ float shsum[2][HF], shmax[2][HF];
    __shared__ float red[3][HF];
    shsum[half][t] = sum;
    shmax[half][t] = mx;
    __syncthreads();
    if (half == 0) {
        sum += shsum[1][t];
        mx = fmaxf(mx, shmax[1][t]);
        float cntf = (float)(s1 - s0);
        float mean = sum / fmaxf(cntf, 1.0f);
        red[0][t] = mean * Wc[t * 3 + 0] + mx * Wc[(HF + t) * 3 + 0] + sum * Wc[(2 * HF + t) * 3 + 0];
        red[1][t] = mean * Wc[t * 3 + 1] + mx * Wc[(HF + t) * 3 + 1] + sum * Wc[(2 * HF + t) * 3 + 1];
        red[2][t] = mean * Wc[t * 3 + 2] + mx * Wc[(HF + t) * 3 + 2] + sum * Wc[(2 * HF + t) * 3 + 2];
    }
    __syncthreads();
    for (int o = 64; o > 0; o >>= 1) {
        if (half == 0 && t < o) {
            red[0][t] += red[0][t + o];
            red[1][t] += red[1][t + o];
            red[2][t] += red[2][t + o];
        }
        __syncthreads();
    }
    if (threadIdx.x < 3) out[g * 3 + threadIdx.x] = red[threadIdx.x][0] + bc[threadIdx.x];
}

extern "C" void kernel_launch(void* const* d_in, const int* in_sizes, int n_in,
                              void* d_out, int out_size, void* d_ws, size_t ws_size,
                              hipStream_t stream) {
    const float* x    = (const float*)d_in[0];
    const int*   ei   = (const int*)d_in[1];
    const int*   batch= (const int*)d_in[2];
    const float* W1   = (const float*)d_in[3];
    const float* b1   = (const float*)d_in[4];
    const float* g1   = (const float*)d_in[5];
    const float* be1  = (const float*)d_in[6];
    const float* W2   = (const float*)d_in[7];
    const float* b2   = (const float*)d_in[8];
    const float* g2   = (const float*)d_in[9];
    const float* be2  = (const float*)d_in[10];
    const float* Wc   = (const float*)d_in[11];
    const float* bc   = (const float*)d_in[12];
    float* out = (float*)d_out;

    const int N = in_sizes[0] / HF;
    const int E = in_sizes[1] / 2;
    const int NG = 256;
    const int* row = ei;
    const int* col = ei + E;
    const int total = N * HF;
    const int nfine = (N + TILE - 1) / TILE;  // <= 512

    // workspace carve-up (256B aligned)
    char* w = (char*)d_ws;
    size_t off = 0;
    auto alloc = [&](size_t bytes) -> void* {
        void* p = w + off;
        off += (bytes + 255) & ~(size_t)255;
        return p;
    };
    int*            cursor    = (int*)alloc((size_t)nfine * 16 * 4);
    float*          dinv      = (float*)alloc((size_t)N * 4);
    int*            rowptr    = (int*)alloc(((size_t)N + 1) * 4);
    int*            gstart    = (int*)alloc((NG + 1) * 4);
    int*            srow      = (int*)alloc((size_t)E * 4);
    float*          ssum1     = (float*)alloc(HF * 4);
    float*          ssq1      = (float*)alloc(HF * 4);
    float*          ssum2     = (float*)alloc(HF * 4);
    float*          ssq2      = (float*)alloc(HF * 4);
    unsigned short* A         = (unsigned short*)alloc((size_t)total * 2);  // dinv-scaled xw (bf16)
    float*          B         = (float*)alloc((size_t)total * 4);           // conv out (f32)
    unsigned*       buckets   = (unsigned*)A;  // aliases A (dead before gemm1)

    const int T256 = 256;
    int gridGa   = (N + 15) / 16;
    int gridGemm = (N + 63) / 64;
    int gridSort = (E + SORT_CHUNK - 1) / SORT_CHUNK;

    // --- CSR build (once; reused by both convs) ---
    hipMemsetAsync(cursor, 0, (size_t)nfine * 16 * 4, stream);
    bucket_sort<<<gridSort, T256, 0, stream>>>(row, col, buckets, cursor, E, nfine);
    tile_place2<<<nfine, T256, 0, stream>>>(buckets, cursor, rowptr, dinv, srow,
                                            batch, gstart, N, NG, nfine);

    // --- conv1 (gemm zeroes conv1 stats buffers; gather; stats) ---
    gemm_rt<<<gridGemm, T256, 0, stream>>>(x, W1, A, nullptr, nullptr, nullptr, nullptr,
                                           dinv, ssum1, ssq1, N, 0);
    gather_conv<<<gridGa, T256, 0, stream>>>(rowptr, srow, dinv, A, b1, B, N);
    bn_stats<<<512, 128, 0, stream>>>(B, ssum1, ssq1, N);

    // --- conv2 (gemm applies BN1 inline from ssum1/ssq1, zeroes conv2 stats) ---
    gemm_rt<<<gridGemm, T256, 0, stream>>>(B, W2, A, ssum1, ssq1, g1, be1,
                                           dinv, ssum2, ssq2, N, 1);
    gather_conv<<<gridGa, T256, 0, stream>>>(rowptr, srow, dinv, A, b2, B, N);
    bn_stats<<<512, 128, 0, stream>>>(B, ssum2, ssq2, N);

    // --- fused BN2(inline)+ReLU + pooling + classifier ---
    pool_classify<<<NG, 256, 0, stream>>>(B, gstart, ssum2, ssq2, g2, be2, Wc, bc, out, N);
}

// Round 14
// 288.376 us; speedup vs baseline: 2.4414x; 1.1728x over previous
//
#include <hip/hip_runtime.h>

#define HF 128       // feature width (F == H == 128)
#define TILE 128     // cols per fine bucket
#define CAP2 6144    // entries per fine bucket (mean ~4096 + slack)
#define NFINE_MAX 512
#define SORT_CHUNK 4096
#define BN_EPS 1e-5f

__device__ __forceinline__ unsigned short f2bf(float f) {
    unsigned u = __float_as_uint(f);
    unsigned rounding = 0x7FFF + ((u >> 16) & 1);  // round-to-nearest-even
    return (unsigned short)((u + rounding) >> 16);
}
__device__ __forceinline__ float bf2f(unsigned short u) {
    return __uint_as_float(((unsigned)u) << 16);
}
__device__ __forceinline__ unsigned packbf(float lo, float hi) {
    return ((unsigned)f2bf(hi) << 16) | (unsigned)f2bf(lo);
}

// ---------- single-pass block counting sort into fine 128-col buckets ----------
__global__ __launch_bounds__(256) void bucket_sort(const int* __restrict__ row,
                                                   const int* __restrict__ col,
                                                   unsigned* __restrict__ buckets,
                                                   int* __restrict__ cursor,  // stride 16 ints
                                                   int E, int nfine) {
    __shared__ int hist[NFINE_MAX], lbase[NFINE_MAX], gbase[NFINE_MAX], lofs[NFINE_MAX];
    __shared__ int s[512];
    __shared__ unsigned staged[SORT_CHUNK];
    __shared__ unsigned short sbkt[SORT_CHUNK];
    int t = threadIdx.x;
    for (int i = t; i < NFINE_MAX; i += 256) { hist[i] = 0; lofs[i] = 0; }
    __syncthreads();
    int e0 = blockIdx.x * SORT_CHUNK;
    int n = min(SORT_CHUNK, E - e0);
    for (int i = t; i < n; i += 256) {
        int c = col[e0 + i];
        atomicAdd(&hist[c >> 7], 1);
    }
    __syncthreads();
    s[t] = hist[t];
    s[t + 256] = hist[t + 256];
    for (int o = 1; o < 512; o <<= 1) {
        __syncthreads();
        int idx = (t + 1) * (o << 1) - 1;
        if (idx < 512) s[idx] += s[idx - o];
    }
    __syncthreads();
    if (t == 0) s[511] = 0;
    for (int o = 256; o >= 1; o >>= 1) {
        __syncthreads();
        int idx = (t + 1) * (o << 1) - 1;
        if (idx < 512) { int tmp = s[idx - o]; s[idx - o] = s[idx]; s[idx] += tmp; }
    }
    __syncthreads();
    lbase[t] = s[t];
    lbase[t + 256] = s[t + 256];
    for (int b = t; b < nfine; b += 256) {
        int cnt = hist[b];
        gbase[b] = cnt ? atomicAdd(&cursor[b * 16], cnt) : 0;
    }
    __syncthreads();
    for (int i = t; i < n; i += 256) {
        int c = col[e0 + i];
        int r = row[e0 + i];
        int b = c >> 7;
        int pos = lbase[b] + atomicAdd(&lofs[b], 1);
        staged[pos] = ((unsigned)(c & 127) << 17) | (unsigned)r;
        sbkt[pos] = (unsigned short)b;
    }
    __syncthreads();
    for (int i = t; i < n; i += 256) {
        int b = sbkt[i];
        int pos = gbase[b] + (i - lbase[b]);
        if (pos < CAP2) buckets[(size_t)b * CAP2 + pos] = staged[i];
    }
}

// ---------- fused per-bucket: own prefix + hist + scan -> rowptr/dinv; place -> srow ----------
// Also folds graph_bounds (blocks 0-1) and rowptr[N]=E (last block).
__global__ __launch_bounds__(256) void tile_place2(const unsigned* __restrict__ buckets,
                                                   const int* __restrict__ cursor,
                                                   int* __restrict__ rowptr,
                                                   float* __restrict__ dinv,
                                                   int* __restrict__ srow,
                                                   const int* __restrict__ batch,
                                                   int* __restrict__ gstart,
                                                   int N, int NG, int nfine) {
    int b = blockIdx.x;
    int t = threadIdx.x;
    if (b < 2 && t < 129) {
        int g = b * 129 + t;
        if (g <= NG) {
            int lo = 0, hi = N;
            while (lo < hi) {
                int mid = (lo + hi) >> 1;
                if (batch[mid] < g) lo = mid + 1; else hi = mid;
            }
            gstart[g] = lo;
        }
    }
    __shared__ int h[TILE], loc[TILE], cur[TILE];
    __shared__ int red[256];
    __shared__ int stage[CAP2];
    int part = 0;
    for (int i = t; i < b; i += 256) part += min(cursor[i * 16], CAP2);
    red[t] = part;
    if (t < TILE) h[t] = 0;
    __syncthreads();
    for (int o = 128; o > 0; o >>= 1) {
        if (t < o) red[t] += red[t + o];
        __syncthreads();
    }
    int base = red[0];
    int sz = min(cursor[b * 16], CAP2);
    const unsigned* bk = buckets + (size_t)b * CAP2;
    for (int i = t; i < sz; i += 256) atomicAdd(&h[bk[i] >> 17], 1);
    __syncthreads();
    if (t < TILE) loc[t] = h[t];
    __syncthreads();
    for (int o = 1; o < TILE; o <<= 1) {
        int v = (t < TILE && t >= o) ? loc[t - o] : 0;
        __syncthreads();
        if (t < TILE) loc[t] += v;
        __syncthreads();
    }
    if (t < TILE) {
        int c = b * TILE + t;
        int excl = loc[t] - h[t];
        if (c < N) {
            rowptr[c] = base + excl;
            dinv[c] = rsqrtf((float)h[t] + 1.0f);
        }
        cur[t] = excl;
    }
    if (b == nfine - 1 && t == 0) rowptr[N] = base + sz;
    __syncthreads();
    for (int i = t; i < sz; i += 256) {
        unsigned p = bk[i];
        int pos = atomicAdd(&cur[p >> 17], 1);
        if (pos < CAP2) stage[pos] = (int)(p & 0x1FFFFu);
    }
    __syncthreads();
    for (int i = t; i < sz; i += 256) srow[base + i] = stage[i];
}

// ---------- register-tiled GEMM: 64-row x 128-col block, 8x4 per thread ----------
// Y(bf16) = rowscale[r] * (BNReLU?(X) @ W). X is f32 when applyBN=0 (conv1 input),
// bf16 when applyBN=1 (conv output B). scale/shift precomputed by bn_reduce.
__global__ __launch_bounds__(256) void gemm_rt(const float* __restrict__ Xf,
                                               const unsigned short* __restrict__ Xh,
                                               const float* __restrict__ W,
                                               unsigned short* __restrict__ Y,
                                               const float* __restrict__ scale,
                                               const float* __restrict__ shift,
                                               const float* __restrict__ rowscale,
                                               int N, int applyBN) {
    __shared__ float xst[HF][68];  // transposed X tile, 272B row stride
    int t = threadIdx.x;
    int row0 = blockIdx.x * 64;
    {
        int f = t & 127;
        float sc = applyBN ? scale[f] : 1.0f;
        float sh = applyBN ? shift[f] : 0.0f;
        for (int r = (t >> 7); r < 64; r += 2) {
            int rr = row0 + r;
            float v = 0.0f;
            if (rr < N) {
                if (applyBN) {
                    v = bf2f(Xh[(size_t)rr * HF + f]);
                    v = fmaxf(v * sc + sh, 0.0f);
                } else {
                    v = Xf[(size_t)rr * HF + f];
                }
            }
            xst[f][r] = v;
        }
    }
    __syncthreads();
    int cg = t & 31;   // cols 4*cg..+3
    int rg = t >> 5;   // rows rg*8..+7
    int r0 = rg * 8;
    float acc[8][4] = {};
    const float4* Wv = reinterpret_cast<const float4*>(W);
    #pragma unroll 2
    for (int f = 0; f < HF; ++f) {
        float4 w = Wv[f * 32 + cg];
        float4 x0 = *reinterpret_cast<const float4*>(&xst[f][r0]);
        float4 x1 = *reinterpret_cast<const float4*>(&xst[f][r0 + 4]);
        float xr[8] = {x0.x, x0.y, x0.z, x0.w, x1.x, x1.y, x1.z, x1.w};
        #pragma unroll
        for (int i = 0; i < 8; ++i) {
            acc[i][0] += xr[i] * w.x;
            acc[i][1] += xr[i] * w.y;
            acc[i][2] += xr[i] * w.z;
            acc[i][3] += xr[i] * w.w;
        }
    }
    #pragma unroll
    for (int i = 0; i < 8; ++i) {
        int rr = row0 + r0 + i;
        if (rr < N) {
            float rs = rowscale[rr];
            ushort4 o;
            o.x = f2bf(acc[i][0] * rs);
            o.y = f2bf(acc[i][1] * rs);
            o.z = f2bf(acc[i][2] * rs);
            o.w = f2bf(acc[i][3] * rs);
            *reinterpret_cast<ushort4*>(&Y[(size_t)rr * HF + cg * 4]) = o;
        }
    }
}

// ---------- gather-side conv (bf16 out) + fused BN partial stats ----------
// 16 lanes/node, 8 feats/lane, 4-deep unroll. Each block reduces its 16 output
// rows to per-feature {sum, sumsq} partials (contiguous 1KB writes, no atomics).
__global__ __launch_bounds__(256) void gather_conv(const int* __restrict__ rowptr,
                                                   const int* __restrict__ srow,
                                                   const float* __restrict__ dinv,
                                                   const unsigned short* __restrict__ XW,
                                                   const float* __restrict__ b,
                                                   unsigned short* __restrict__ OUT,
                                                   float* __restrict__ psum,
                                                   float* __restrict__ psq, int N) {
    int blk = blockIdx.x;
    int c = blk * 16 + (threadIdx.x >> 4);
    int j = threadIdx.x & 15;  // 8 features per lane
    bool valid = (c < N);
    const unsigned M = 0xffff0000u;
    float o[8];
    if (valid) {
        int e = rowptr[c], end = rowptr[c + 1];
        float acc[8] = {0.f, 0.f, 0.f, 0.f, 0.f, 0.f, 0.f, 0.f};
        for (; e + 3 < end; e += 4) {
            int r0 = srow[e], r1 = srow[e + 1], r2 = srow[e + 2], r3 = srow[e + 3];
            uint4 u0 = *reinterpret_cast<const uint4*>(XW + (size_t)r0 * HF + j * 8);
            uint4 u1 = *reinterpret_cast<const uint4*>(XW + (size_t)r1 * HF + j * 8);
            uint4 u2 = *reinterpret_cast<const uint4*>(XW + (size_t)r2 * HF + j * 8);
            uint4 u3 = *reinterpret_cast<const uint4*>(XW + (size_t)r3 * HF + j * 8);
            acc[0] += (__uint_as_float(u0.x << 16) + __uint_as_float(u1.x << 16))
                    + (__uint_as_float(u2.x << 16) + __uint_as_float(u3.x << 16));
            acc[1] += (__uint_as_float(u0.x & M) + __uint_as_float(u1.x & M))
                    + (__uint_as_float(u2.x & M) + __uint_as_float(u3.x & M));
            acc[2] += (__uint_as_float(u0.y << 16) + __uint_as_float(u1.y << 16))
                    + (__uint_as_float(u2.y << 16) + __uint_as_float(u3.y << 16));
            acc[3] += (__uint_as_float(u0.y & M) + __uint_as_float(u1.y & M))
                    + (__uint_as_float(u2.y & M) + __uint_as_float(u3.y & M));
            acc[4] += (__uint_as_float(u0.z << 16) + __uint_as_float(u1.z << 16))
                    + (__uint_as_float(u2.z << 16) + __uint_as_float(u3.z << 16));
            acc[5] += (__uint_as_float(u0.z & M) + __uint_as_float(u1.z & M))
                    + (__uint_as_float(u2.z & M) + __uint_as_float(u3.z & M));
            acc[6] += (__uint_as_float(u0.w << 16) + __uint_as_float(u1.w << 16))
                    + (__uint_as_float(u2.w << 16) + __uint_as_float(u3.w << 16));
            acc[7] += (__uint_as_float(u0.w & M) + __uint_as_float(u1.w & M))
                    + (__uint_as_float(u2.w & M) + __uint_as_float(u3.w & M));
        }
        for (; e < end; ++e) {
            int r0 = srow[e];
            uint4 u0 = *reinterpret_cast<const uint4*>(XW + (size_t)r0 * HF + j * 8);
            acc[0] += __uint_as_float(u0.x << 16);
            acc[1] += __uint_as_float(u0.x & M);
            acc[2] += __uint_as_float(u0.y << 16);
            acc[3] += __uint_as_float(u0.y & M);
            acc[4] += __uint_as_float(u0.z << 16);
            acc[5] += __uint_as_float(u0.z & M);
            acc[6] += __uint_as_float(u0.w << 16);
            acc[7] += __uint_as_float(u0.w & M);
        }
        float dc = dinv[c];
        uint4 xv = *reinterpret_cast<const uint4*>(XW + (size_t)c * HF + j * 8);
        acc[0] += __uint_as_float(xv.x << 16);
        acc[1] += __uint_as_float(xv.x & M);
        acc[2] += __uint_as_float(xv.y << 16);
        acc[3] += __uint_as_float(xv.y & M);
        acc[4] += __uint_as_float(xv.z << 16);
        acc[5] += __uint_as_float(xv.z & M);
        acc[6] += __uint_as_float(xv.w << 16);
        acc[7] += __uint_as_float(xv.w & M);
        float4 b0 = *reinterpret_cast<const float4*>(b + j * 8);
        float4 b1 = *reinterpret_cast<const float4*>(b + j * 8 + 4);
        float dcv = dc;
        o[0] = dcv * acc[0] + b0.x;
        o[1] = dcv * acc[1] + b0.y;
        o[2] = dcv * acc[2] + b0.z;
        o[3] = dcv * acc[3] + b0.w;
        o[4] = dcv * acc[4] + b1.x;
        o[5] = dcv * acc[5] + b1.y;
        o[6] = dcv * acc[6] + b1.z;
        o[7] = dcv * acc[7] + b1.w;
        uint4 ov;
        ov.x = packbf(o[0], o[1]);
        ov.y = packbf(o[2], o[3]);
        ov.z = packbf(o[4], o[5]);
        ov.w = packbf(o[6], o[7]);
        *reinterpret_cast<uint4*>(OUT + (size_t)c * HF + j * 8) = ov;
    } else {
        #pragma unroll
        for (int k = 0; k < 8; ++k) o[k] = 0.f;
    }
    // fused BN partials: stage rows in LDS, reduce over the block's 16 rows
    __shared__ float sval[16][HF + 4];
    int r = threadIdx.x >> 4;
    *reinterpret_cast<float4*>(&sval[r][j * 8]) = make_float4(o[0], o[1], o[2], o[3]);
    *reinterpret_cast<float4*>(&sval[r][j * 8 + 4]) = make_float4(o[4], o[5], o[6], o[7]);
    __syncthreads();
    if (threadIdx.x < HF) {
        float s = 0.f, sq = 0.f;
        #pragma unroll
        for (int rr = 0; rr < 16; ++rr) {
            float v = sval[rr][threadIdx.x];
            s += v;
            sq += v * v;
        }
        psum[(size_t)blk * HF + threadIdx.x] = s;
        psq[(size_t)blk * HF + threadIdx.x] = sq;
    }
}

// ---------- BN reduce (partials -> scale/shift) ----------
__global__ __launch_bounds__(256) void bn_reduce(const float* __restrict__ psum,
                                                 const float* __restrict__ psq,
                                                 const float* __restrict__ gamma,
                                                 const float* __restrict__ beta,
                                                 float* __restrict__ scale,
                                                 float* __restrict__ shift,
                                                 int nblk, int N) {
    int f = blockIdx.x;  // one block per feature
    int t = threadIdx.x;
    float s = 0.f, sq = 0.f;
    for (int i = t; i < nblk; i += 256) {
        s += psum[(size_t)i * HF + f];
        sq += psq[(size_t)i * HF + f];
    }
    __shared__ float ls[256], lq[256];
    ls[t] = s; lq[t] = sq;
    __syncthreads();
    for (int o = 128; o > 0; o >>= 1) {
        if (t < o) { ls[t] += ls[t + o]; lq[t] += lq[t + o]; }
        __syncthreads();
    }
    if (t == 0) {
        float invn = 1.0f / (float)N;
        float mu = ls[0] * invn;
        float var = lq[0] * invn - mu * mu;
        float sc = gamma[f] * rsqrtf(var + BN_EPS);
        scale[f] = sc;
        shift[f] = beta[f] - mu * sc;
    }
}

// ---------- fused BN2+ReLU + mean/max/sum pool + classifier (bf16 B input) ----------
__global__ __launch_bounds__(256) void pool_classify(const unsigned short* __restrict__ Bh,
                                                     const int* __restrict__ gstart,
                                                     const float* __restrict__ scale,
                                                     const float* __restrict__ shift,
                                                     const float* __restrict__ Wc,
                                                     const float* __restrict__ bc,
                                                     float* __restrict__ out) {
    int g = blockIdx.x;
    int t = threadIdx.x & 127;
    int half = threadIdx.x >> 7;
    int s0 = gstart[g], s1 = gstart[g + 1];
    float sc = scale[t], sh = shift[t];
    float sum = 0.f, mx = 0.f;  // 0-init == empty-graph guard (post-ReLU v >= 0)
    for (int n = s0 + half; n < s1; n += 2) {
        float v = fmaxf(bf2f(Bh[(size_t)n * HF + t]) * sc + sh, 0.0f);
        sum += v;
        mx = fmaxf(mx, v);
    }
    __shared__ float shsum[2][HF], shmax[2][HF];
    __shared__ float red[3][HF];
    shsum[half][t] = sum;
    shmax[half][t] = mx;
    __syncthreads();
    if (half == 0) {
        sum += shsum[1][t];
        mx = fmaxf(mx, shmax[1][t]);
        float cntf = (float)(s1 - s0);
        float mean = sum / fmaxf(cntf, 1.0f);
        red[0][t] = mean * Wc[t * 3 + 0] + mx * Wc[(HF + t) * 3 + 0] + sum * Wc[(2 * HF + t) * 3 + 0];
        red[1][t] = mean * Wc[t * 3 + 1] + mx * Wc[(HF + t) * 3 + 1] + sum * Wc[(2 * HF + t) * 3 + 1];
        red[2][t] = mean * Wc[t * 3 + 2] + mx * Wc[(HF + t) * 3 + 2] + sum * Wc[(2 * HF + t) * 3 + 2];
    }
    __syncthreads();
    for (int o = 64; o > 0; o >>= 1) {
        if (half == 0 && t < o) {
            red[0][t] += red[0][t + o];
            red[1][t] += red[1][t + o];
            red[2][t] += red[2][t + o];
        }
        __syncthreads();
    }
    if (threadIdx.x < 3) out[g * 3 + threadIdx.x] = red[threadIdx.x][0] + bc[threadIdx.x];
}

extern "C" void kernel_launch(void* const* d_in, const int* in_sizes, int n_in,
                              void* d_out, int out_size, void* d_ws, size_t ws_size,
                              hipStream_t stream) {
    const float* x    = (const float*)d_in[0];
    const int*   ei   = (const int*)d_in[1];
    const int*   batch= (const int*)d_in[2];
    const float* W1   = (const float*)d_in[3];
    const float* b1   = (const float*)d_in[4];
    const float* g1   = (const float*)d_in[5];
    const float* be1  = (const float*)d_in[6];
    const float* W2   = (const float*)d_in[7];
    const float* b2   = (const float*)d_in[8];
    const float* g2   = (const float*)d_in[9];
    const float* be2  = (const float*)d_in[10];
    const float* Wc   = (const float*)d_in[11];
    const float* bc   = (const float*)d_in[12];
    float* out = (float*)d_out;

    const int N = in_sizes[0] / HF;
    const int E = in_sizes[1] / 2;
    const int NG = 256;
    const int* row = ei;
    const int* col = ei + E;
    const int total = N * HF;
    const int nfine = (N + TILE - 1) / TILE;  // <= 512
    const int nblkGa = (N + 15) / 16;

    // workspace carve-up (256B aligned); total ~35.8MB (known-good <= 45.2MB)
    char* w = (char*)d_ws;
    size_t off = 0;
    auto alloc = [&](size_t bytes) -> void* {
        void* p = w + off;
        off += (bytes + 255) & ~(size_t)255;
        return p;
    };
    int*            cursor    = (int*)alloc((size_t)nfine * 16 * 4);
    float*          dinv      = (float*)alloc((size_t)N * 4);
    int*            rowptr    = (int*)alloc(((size_t)N + 1) * 4);
    int*            gstart    = (int*)alloc((NG + 1) * 4);
    int*            srow      = (int*)alloc((size_t)E * 4);
    float*          psum      = (float*)alloc((size_t)nblkGa * HF * 4);
    float*          psq       = (float*)alloc((size_t)nblkGa * HF * 4);
    float*          scale     = (float*)alloc(HF * 4);
    float*          shift     = (float*)alloc(HF * 4);
    unsigned short* A         = (unsigned short*)alloc((size_t)total * 2);  // dinv-scaled xw (bf16)
    unsigned short* B         = (unsigned short*)alloc((size_t)total * 2);  // conv out (bf16)
    unsigned*       buckets   = (unsigned*)A;  // aliases A (dead before gemm1)

    const int T256 = 256;
    int gridGemm = (N + 63) / 64;
    int gridSort = (E + SORT_CHUNK - 1) / SORT_CHUNK;

    // --- CSR build (once; reused by both convs) ---
    hipMemsetAsync(cursor, 0, (size_t)nfine * 16 * 4, stream);
    bucket_sort<<<gridSort, T256, 0, stream>>>(row, col, buckets, cursor, E, nfine);
    tile_place2<<<nfine, T256, 0, stream>>>(buckets, cursor, rowptr, dinv, srow,
                                            batch, gstart, N, NG, nfine);

    // --- conv1 ---
    gemm_rt<<<gridGemm, T256, 0, stream>>>(x, nullptr, W1, A, nullptr, nullptr, dinv, N, 0);
    gather_conv<<<nblkGa, T256, 0, stream>>>(rowptr, srow, dinv, A, b1, B, psum, psq, N);
    bn_reduce<<<HF, 256, 0, stream>>>(psum, psq, g1, be1, scale, shift, nblkGa, N);

    // --- conv2 (BN1+ReLU fused into gemm input load, bf16 X) ---
    gemm_rt<<<gridGemm, T256, 0, stream>>>(nullptr, B, W2, A, scale, shift, dinv, N, 1);
    gather_conv<<<nblkGa, T256, 0, stream>>>(rowptr, srow, dinv, A, b2, B, psum, psq, N);
    bn_reduce<<<HF, 256, 0, stream>>>(psum, psq, g2, be2, scale, shift, nblkGa, N);

    // --- fused BN2+ReLU + pooling + classifier ---
    pool_classify<<<NG, 256, 0, stream>>>(B, gstart, scale, shift, Wc, bc, out);
}

// Round 15
// 282.159 us; speedup vs baseline: 2.4952x; 1.0220x over previous
//
#include <hip/hip_runtime.h>

#define HF 128       // feature width (F == H == 128)
#define TILE 128     // cols per fine bucket
#define CAP2 6144    // entries per fine bucket (mean ~4096 + slack)
#define NFINE_MAX 512
#define SORT_CHUNK 4096
#define BN_EPS 1e-5f
#define SMEM_BYTES 34816  // sort layout == gemm xst[128][68] floats

__device__ __forceinline__ unsigned short f2bf(float f) {
    unsigned u = __float_as_uint(f);
    unsigned rounding = 0x7FFF + ((u >> 16) & 1);  // round-to-nearest-even
    return (unsigned short)((u + rounding) >> 16);
}
__device__ __forceinline__ float bf2f(unsigned short u) {
    return __uint_as_float(((unsigned)u) << 16);
}
__device__ __forceinline__ unsigned packbf(float lo, float hi) {
    return ((unsigned)f2bf(hi) << 16) | (unsigned)f2bf(lo);
}

// ---------- bucket_sort block body (LDS laid out manually in smem) ----------
__device__ __forceinline__ void bucket_sort_block(char* smem, int bid,
                                                  const int* __restrict__ row,
                                                  const int* __restrict__ col,
                                                  unsigned* __restrict__ buckets,
                                                  int* __restrict__ cursor,
                                                  int E, int nfine) {
    unsigned* staged = (unsigned*)smem;                      // 16KB
    unsigned short* sbkt = (unsigned short*)(smem + 16384);  // 8KB
    int* hist  = (int*)(smem + 24576);
    int* lbase = (int*)(smem + 26624);
    int* gbase = (int*)(smem + 28672);
    int* lofs  = (int*)(smem + 30720);
    int* s     = (int*)(smem + 32768);
    int t = threadIdx.x;
    for (int i = t; i < NFINE_MAX; i += 256) { hist[i] = 0; lofs[i] = 0; }
    __syncthreads();
    int e0 = bid * SORT_CHUNK;
    int n = min(SORT_CHUNK, E - e0);
    for (int i = t; i < n; i += 256) {
        int c = col[e0 + i];
        atomicAdd(&hist[c >> 7], 1);
    }
    __syncthreads();
    s[t] = hist[t];
    s[t + 256] = hist[t + 256];
    for (int o = 1; o < 512; o <<= 1) {
        __syncthreads();
        int idx = (t + 1) * (o << 1) - 1;
        if (idx < 512) s[idx] += s[idx - o];
    }
    __syncthreads();
    if (t == 0) s[511] = 0;
    for (int o = 256; o >= 1; o >>= 1) {
        __syncthreads();
        int idx = (t + 1) * (o << 1) - 1;
        if (idx < 512) { int tmp = s[idx - o]; s[idx - o] = s[idx]; s[idx] += tmp; }
    }
    __syncthreads();
    lbase[t] = s[t];
    lbase[t + 256] = s[t + 256];
    for (int b = t; b < nfine; b += 256) {
        int cnt = hist[b];
        gbase[b] = cnt ? atomicAdd(&cursor[b * 16], cnt) : 0;
    }
    __syncthreads();
    for (int i = t; i < n; i += 256) {
        int c = col[e0 + i];
        int r = row[e0 + i];
        int b = c >> 7;
        int pos = lbase[b] + atomicAdd(&lofs[b], 1);
        staged[pos] = ((unsigned)(c & 127) << 17) | (unsigned)r;
        sbkt[pos] = (unsigned short)b;
    }
    __syncthreads();
    for (int i = t; i < n; i += 256) {
        int b = sbkt[i];
        int pos = gbase[b] + (i - lbase[b]);
        if (pos < CAP2) buckets[(size_t)b * CAP2 + pos] = staged[i];
    }
}

// ---------- gemm block body: 64x128 tile, 8x4/thread; optional rowscale ----------
__device__ __forceinline__ void gemm_block(char* smem, int bid,
                                           const float* __restrict__ Xf,
                                           const unsigned short* __restrict__ Xh,
                                           const float* __restrict__ W,
                                           unsigned short* __restrict__ Y,
                                           const float* __restrict__ scale,
                                           const float* __restrict__ shift,
                                           const float* __restrict__ rowscale,
                                           int N, int applyBN) {
    float (*xst)[68] = (float(*)[68])smem;  // [128][68], 272B row stride
    int t = threadIdx.x;
    int row0 = bid * 64;
    {
        int f = t & 127;
        float sc = applyBN ? scale[f] : 1.0f;
        float sh = applyBN ? shift[f] : 0.0f;
        for (int r = (t >> 7); r < 64; r += 2) {
            int rr = row0 + r;
            float v = 0.0f;
            if (rr < N) {
                if (applyBN) {
                    v = bf2f(Xh[(size_t)rr * HF + f]);
                    v = fmaxf(v * sc + sh, 0.0f);
                } else {
                    v = Xf[(size_t)rr * HF + f];
                }
            }
            xst[f][r] = v;
        }
    }
    __syncthreads();
    int cg = t & 31;
    int rg = t >> 5;
    int r0 = rg * 8;
    float acc[8][4] = {};
    const float4* Wv = reinterpret_cast<const float4*>(W);
    #pragma unroll 2
    for (int f = 0; f < HF; ++f) {
        float4 w = Wv[f * 32 + cg];
        float4 x0 = *reinterpret_cast<const float4*>(&xst[f][r0]);
        float4 x1 = *reinterpret_cast<const float4*>(&xst[f][r0 + 4]);
        float xr[8] = {x0.x, x0.y, x0.z, x0.w, x1.x, x1.y, x1.z, x1.w};
        #pragma unroll
        for (int i = 0; i < 8; ++i) {
            acc[i][0] += xr[i] * w.x;
            acc[i][1] += xr[i] * w.y;
            acc[i][2] += xr[i] * w.z;
            acc[i][3] += xr[i] * w.w;
        }
    }
    #pragma unroll
    for (int i = 0; i < 8; ++i) {
        int rr = row0 + r0 + i;
        if (rr < N) {
            float rs = rowscale ? rowscale[rr] : 1.0f;
            ushort4 o;
            o.x = f2bf(acc[i][0] * rs);
            o.y = f2bf(acc[i][1] * rs);
            o.z = f2bf(acc[i][2] * rs);
            o.w = f2bf(acc[i][3] * rs);
            *reinterpret_cast<ushort4*>(&Y[(size_t)rr * HF + cg * 4]) = o;
        }
    }
}

// ---------- fused: bucket_sort (blocks < nsort) || gemm1 UNSCALED (rest) ----------
// Legal: buckets alias B (dead until gather1) while gemm writes A. dinv is not
// available yet, so gemm1 writes unscaled xw; scale_rows applies dinv after
// tile_place2 computes it.
__global__ __launch_bounds__(256) void sort_gemm1(const int* __restrict__ row,
                                                  const int* __restrict__ col,
                                                  unsigned* __restrict__ buckets,
                                                  int* __restrict__ cursor,
                                                  int E, int nfine, int nsort,
                                                  const float* __restrict__ x,
                                                  const float* __restrict__ W1,
                                                  unsigned short* __restrict__ A,
                                                  int N) {
    __shared__ __align__(16) char smem[SMEM_BYTES];
    if (blockIdx.x < nsort)
        bucket_sort_block(smem, blockIdx.x, row, col, buckets, cursor, E, nfine);
    else
        gemm_block(smem, blockIdx.x - nsort, x, nullptr, W1, A,
                   nullptr, nullptr, nullptr, N, 0);
}

// ---------- standalone gemm (conv2: BN1+ReLU on bf16 input, dinv rowscale) ----------
__global__ __launch_bounds__(256) void gemm_rt(const unsigned short* __restrict__ Xh,
                                               const float* __restrict__ W,
                                               unsigned short* __restrict__ Y,
                                               const float* __restrict__ scale,
                                               const float* __restrict__ shift,
                                               const float* __restrict__ rowscale,
                                               int N) {
    __shared__ __align__(16) char smem[SMEM_BYTES];
    gemm_block(smem, blockIdx.x, nullptr, Xh, W, Y, scale, shift, rowscale, N, 1);
}

// ---------- scale A rows by dinv (bf16 in-place), 8 elems/thread ----------
__global__ __launch_bounds__(256) void scale_rows(unsigned short* __restrict__ A,
                                                  const float* __restrict__ dinv,
                                                  int N) {
    int idx = blockIdx.x * 256 + threadIdx.x;       // one thread = 8 elems
    int n = idx >> 4, j = idx & 15;
    if (n >= N) return;
    float dc = dinv[n];
    const unsigned M = 0xffff0000u;
    uint4 u = *reinterpret_cast<const uint4*>(A + (size_t)n * HF + j * 8);
    uint4 o;
    o.x = packbf(__uint_as_float(u.x << 16) * dc, __uint_as_float(u.x & M) * dc);
    o.y = packbf(__uint_as_float(u.y << 16) * dc, __uint_as_float(u.y & M) * dc);
    o.z = packbf(__uint_as_float(u.z << 16) * dc, __uint_as_float(u.z & M) * dc);
    o.w = packbf(__uint_as_float(u.w << 16) * dc, __uint_as_float(u.w & M) * dc);
    *reinterpret_cast<uint4*>(A + (size_t)n * HF + j * 8) = o;
}

// ---------- fused per-bucket CSR place (+graph_bounds, +rowptr[N]) ----------
__global__ __launch_bounds__(256) void tile_place2(const unsigned* __restrict__ buckets,
                                                   const int* __restrict__ cursor,
                                                   int* __restrict__ rowptr,
                                                   float* __restrict__ dinv,
                                                   int* __restrict__ srow,
                                                   const int* __restrict__ batch,
                                                   int* __restrict__ gstart,
                                                   int N, int NG, int nfine) {
    int b = blockIdx.x;
    int t = threadIdx.x;
    if (b < 2 && t < 129) {
        int g = b * 129 + t;
        if (g <= NG) {
            int lo = 0, hi = N;
            while (lo < hi) {
                int mid = (lo + hi) >> 1;
                if (batch[mid] < g) lo = mid + 1; else hi = mid;
            }
            gstart[g] = lo;
        }
    }
    __shared__ int h[TILE], loc[TILE], cur[TILE];
    __shared__ int red[256];
    __shared__ int stage[CAP2];
    int part = 0;
    for (int i = t; i < b; i += 256) part += min(cursor[i * 16], CAP2);
    red[t] = part;
    if (t < TILE) h[t] = 0;
    __syncthreads();
    for (int o = 128; o > 0; o >>= 1) {
        if (t < o) red[t] += red[t + o];
        __syncthreads();
    }
    int base = red[0];
    int sz = min(cursor[b * 16], CAP2);
    const unsigned* bk = buckets + (size_t)b * CAP2;
    for (int i = t; i < sz; i += 256) atomicAdd(&h[bk[i] >> 17], 1);
    __syncthreads();
    if (t < TILE) loc[t] = h[t];
    __syncthreads();
    for (int o = 1; o < TILE; o <<= 1) {
        int v = (t < TILE && t >= o) ? loc[t - o] : 0;
        __syncthreads();
        if (t < TILE) loc[t] += v;
        __syncthreads();
    }
    if (t < TILE) {
        int c = b * TILE + t;
        int excl = loc[t] - h[t];
        if (c < N) {
            rowptr[c] = base + excl;
            dinv[c] = rsqrtf((float)h[t] + 1.0f);
        }
        cur[t] = excl;
    }
    if (b == nfine - 1 && t == 0) rowptr[N] = base + sz;
    __syncthreads();
    for (int i = t; i < sz; i += 256) {
        unsigned p = bk[i];
        int pos = atomicAdd(&cur[p >> 17], 1);
        if (pos < CAP2) stage[pos] = (int)(p & 0x1FFFFu);
    }
    __syncthreads();
    for (int i = t; i < sz; i += 256) srow[base + i] = stage[i];
}

// ---------- gather-side conv (bf16 out) + fused BN partial stats ----------
__global__ __launch_bounds__(256) void gather_conv(const int* __restrict__ rowptr,
                                                   const int* __restrict__ srow,
                                                   const float* __restrict__ dinv,
                                                   const unsigned short* __restrict__ XW,
                                                   const float* __restrict__ b,
                                                   unsigned short* __restrict__ OUT,
                                                   float* __restrict__ psum,
                                                   float* __restrict__ psq, int N) {
    int blk = blockIdx.x;
    int c = blk * 16 + (threadIdx.x >> 4);
    int j = threadIdx.x & 15;  // 8 features per lane
    bool valid = (c < N);
    const unsigned M = 0xffff0000u;
    float o[8];
    if (valid) {
        int e = rowptr[c], end = rowptr[c + 1];
        float acc[8] = {0.f, 0.f, 0.f, 0.f, 0.f, 0.f, 0.f, 0.f};
        for (; e + 3 < end; e += 4) {
            int r0 = srow[e], r1 = srow[e + 1], r2 = srow[e + 2], r3 = srow[e + 3];
            uint4 u0 = *reinterpret_cast<const uint4*>(XW + (size_t)r0 * HF + j * 8);
            uint4 u1 = *reinterpret_cast<const uint4*>(XW + (size_t)r1 * HF + j * 8);
            uint4 u2 = *reinterpret_cast<const uint4*>(XW + (size_t)r2 * HF + j * 8);
            uint4 u3 = *reinterpret_cast<const uint4*>(XW + (size_t)r3 * HF + j * 8);
            acc[0] += (__uint_as_float(u0.x << 16) + __uint_as_float(u1.x << 16))
                    + (__uint_as_float(u2.x << 16) + __uint_as_float(u3.x << 16));
            acc[1] += (__uint_as_float(u0.x & M) + __uint_as_float(u1.x & M))
                    + (__uint_as_float(u2.x & M) + __uint_as_float(u3.x & M));
            acc[2] += (__uint_as_float(u0.y << 16) + __uint_as_float(u1.y << 16))
                    + (__uint_as_float(u2.y << 16) + __uint_as_float(u3.y << 16));
            acc[3] += (__uint_as_float(u0.y & M) + __uint_as_float(u1.y & M))
                    + (__uint_as_float(u2.y & M) + __uint_as_float(u3.y & M));
            acc[4] += (__uint_as_float(u0.z << 16) + __uint_as_float(u1.z << 16))
                    + (__uint_as_float(u2.z << 16) + __uint_as_float(u3.z << 16));
            acc[5] += (__uint_as_float(u0.z & M) + __uint_as_float(u1.z & M))
                    + (__uint_as_float(u2.z & M) + __uint_as_float(u3.z & M));
            acc[6] += (__uint_as_float(u0.w << 16) + __uint_as_float(u1.w << 16))
                    + (__uint_as_float(u2.w << 16) + __uint_as_float(u3.w << 16));
            acc[7] += (__uint_as_float(u0.w & M) + __uint_as_float(u1.w & M))
                    + (__uint_as_float(u2.w & M) + __uint_as_float(u3.w & M));
        }
        for (; e < end; ++e) {
            int r0 = srow[e];
            uint4 u0 = *reinterpret_cast<const uint4*>(XW + (size_t)r0 * HF + j * 8);
            acc[0] += __uint_as_float(u0.x << 16);
            acc[1] += __uint_as_float(u0.x & M);
            acc[2] += __uint_as_float(u0.y << 16);
            acc[3] += __uint_as_float(u0.y & M);
            acc[4] += __uint_as_float(u0.z << 16);
            acc[5] += __uint_as_float(u0.z & M);
            acc[6] += __uint_as_float(u0.w << 16);
            acc[7] += __uint_as_float(u0.w & M);
        }
        float dc = dinv[c];
        uint4 xv = *reinterpret_cast<const uint4*>(XW + (size_t)c * HF + j * 8);
        acc[0] += __uint_as_float(xv.x << 16);
        acc[1] += __uint_as_float(xv.x & M);
        acc[2] += __uint_as_float(xv.y << 16);
        acc[3] += __uint_as_float(xv.y & M);
        acc[4] += __uint_as_float(xv.z << 16);
        acc[5] += __uint_as_float(xv.z & M);
        acc[6] += __uint_as_float(xv.w << 16);
        acc[7] += __uint_as_float(xv.w & M);
        float4 b0 = *reinterpret_cast<const float4*>(b + j * 8);
        float4 b1 = *reinterpret_cast<const float4*>(b + j * 8 + 4);
        o[0] = dc * acc[0] + b0.x;
        o[1] = dc * acc[1] + b0.y;
        o[2] = dc * acc[2] + b0.z;
        o[3] = dc * acc[3] + b0.w;
        o[4] = dc * acc[4] + b1.x;
        o[5] = dc * acc[5] + b1.y;
        o[6] = dc * acc[6] + b1.z;
        o[7] = dc * acc[7] + b1.w;
        uint4 ov;
        ov.x = packbf(o[0], o[1]);
        ov.y = packbf(o[2], o[3]);
        ov.z = packbf(o[4], o[5]);
        ov.w = packbf(o[6], o[7]);
        *reinterpret_cast<uint4*>(OUT + (size_t)c * HF + j * 8) = ov;
    } else {
        #pragma unroll
        for (int k = 0; k < 8; ++k) o[k] = 0.f;
    }
    __shared__ float sval[16][HF + 4];
    int r = threadIdx.x >> 4;
    *reinterpret_cast<float4*>(&sval[r][j * 8]) = make_float4(o[0], o[1], o[2], o[3]);
    *reinterpret_cast<float4*>(&sval[r][j * 8 + 4]) = make_float4(o[4], o[5], o[6], o[7]);
    __syncthreads();
    if (threadIdx.x < HF) {
        float s = 0.f, sq = 0.f;
        #pragma unroll
        for (int rr = 0; rr < 16; ++rr) {
            float v = sval[rr][threadIdx.x];
            s += v;
            sq += v * v;
        }
        psum[(size_t)blk * HF + threadIdx.x] = s;
        psq[(size_t)blk * HF + threadIdx.x] = sq;
    }
}

// ---------- BN reduce (partials -> scale/shift) ----------
__global__ __launch_bounds__(256) void bn_reduce(const float* __restrict__ psum,
                                                 const float* __restrict__ psq,
                                                 const float* __restrict__ gamma,
                                                 const float* __restrict__ beta,
                                                 float* __restrict__ scale,
                                                 float* __restrict__ shift,
                                                 int nblk, int N) {
    int f = blockIdx.x;
    int t = threadIdx.x;
    float s = 0.f, sq = 0.f;
    for (int i = t; i < nblk; i += 256) {
        s += psum[(size_t)i * HF + f];
        sq += psq[(size_t)i * HF + f];
    }
    __shared__ float ls[256], lq[256];
    ls[t] = s; lq[t] = sq;
    __syncthreads();
    for (int o = 128; o > 0; o >>= 1) {
        if (t < o) { ls[t] += ls[t + o]; lq[t] += lq[t + o]; }
        __syncthreads();
    }
    if (t == 0) {
        float invn = 1.0f / (float)N;
        float mu = ls[0] * invn;
        float var = lq[0] * invn - mu * mu;
        float sc = gamma[f] * rsqrtf(var + BN_EPS);
        scale[f] = sc;
        shift[f] = beta[f] - mu * sc;
    }
}

// ---------- fused BN2+ReLU + mean/max/sum pool + classifier (bf16 B) ----------
__global__ __launch_bounds__(256) void pool_classify(const unsigned short* __restrict__ Bh,
                                                     const int* __restrict__ gstart,
                                                     const float* __restrict__ scale,
                                                     const float* __restrict__ shift,
                                                     const float* __restrict__ Wc,
                                                     const float* __restrict__ bc,
                                                     float* __restrict__ out) {
    int g = blockIdx.x;
    int t = threadIdx.x & 127;
    int half = threadIdx.x >> 7;
    int s0 = gstart[g], s1 = gstart[g + 1];
    float sc = scale[t], sh = shift[t];
    float sum = 0.f, mx = 0.f;  // 0-init == empty-graph guard
    for (int n = s0 + half; n < s1; n += 2) {
        float v = fmaxf(bf2f(Bh[(size_t)n * HF + t]) * sc + sh, 0.0f);
        sum += v;
        mx = fmaxf(mx, v);
    }
    __shared__ float shsum[2][HF], shmax[2][HF];
    __shared__ float red[3][HF];
    shsum[half][t] = sum;
    shmax[half][t] = mx;
    __syncthreads();
    if (half == 0) {
        sum += shsum[1][t];
        mx = fmaxf(mx, shmax[1][t]);
        float cntf = (float)(s1 - s0);
        float mean = sum / fmaxf(cntf, 1.0f);
        red[0][t] = mean * Wc[t * 3 + 0] + mx * Wc[(HF + t) * 3 + 0] + sum * Wc[(2 * HF + t) * 3 + 0];
        red[1][t] = mean * Wc[t * 3 + 1] + mx * Wc[(HF + t) * 3 + 1] + sum * Wc[(2 * HF + t) * 3 + 1];
        red[2][t] = mean * Wc[t * 3 + 2] + mx * Wc[(HF + t) * 3 + 2] + sum * Wc[(2 * HF + t) * 3 + 2];
    }
    __syncthreads();
    for (int o = 64; o > 0; o >>= 1) {
        if (half == 0 && t < o) {
            red[0][t] += red[0][t + o];
            red[1][t] += red[1][t + o];
            red[2][t] += red[2][t + o];
        }
        __syncthreads();
    }
    if (threadIdx.x < 3) out[g * 3 + threadIdx.x] = red[threadIdx.x][0] + bc[threadIdx.x];
}

extern "C" void kernel_launch(void* const* d_in, const int* in_sizes, int n_in,
                              void* d_out, int out_size, void* d_ws, size_t ws_size,
                              hipStream_t stream) {
    const float* x    = (const float*)d_in[0];
    const int*   ei   = (const int*)d_in[1];
    const int*   batch= (const int*)d_in[2];
    const float* W1   = (const float*)d_in[3];
    const float* b1   = (const float*)d_in[4];
    const float* g1   = (const float*)d_in[5];
    const float* be1  = (const float*)d_in[6];
    const float* W2   = (const float*)d_in[7];
    const float* b2   = (const float*)d_in[8];
    const float* g2   = (const float*)d_in[9];
    const float* be2  = (const float*)d_in[10];
    const float* Wc   = (const float*)d_in[11];
    const float* bc   = (const float*)d_in[12];
    float* out = (float*)d_out;

    const int N = in_sizes[0] / HF;
    const int E = in_sizes[1] / 2;
    const int NG = 256;
    const int* row = ei;
    const int* col = ei + E;
    const int total = N * HF;
    const int nfine = (N + TILE - 1) / TILE;  // <= 512
    const int nblkGa = (N + 15) / 16;

    // workspace carve-up (256B aligned); total ~35.8MB (known-good <= 45.2MB)
    char* w = (char*)d_ws;
    size_t off = 0;
    auto alloc = [&](size_t bytes) -> void* {
        void* p = w + off;
        off += (bytes + 255) & ~(size_t)255;
        return p;
    };
    int*            cursor    = (int*)alloc((size_t)nfine * 16 * 4);
    float*          dinv      = (float*)alloc((size_t)N * 4);
    int*            rowptr    = (int*)alloc(((size_t)N + 1) * 4);
    int*            gstart    = (int*)alloc((NG + 1) * 4);
    int*            srow      = (int*)alloc((size_t)E * 4);
    float*          psum      = (float*)alloc((size_t)nblkGa * HF * 4);
    float*          psq       = (float*)alloc((size_t)nblkGa * HF * 4);
    float*          scale     = (float*)alloc(HF * 4);
    float*          shift     = (float*)alloc(HF * 4);
    unsigned short* A         = (unsigned short*)alloc((size_t)total * 2);  // xw (bf16)
    unsigned short* B         = (unsigned short*)alloc((size_t)total * 2);  // conv out (bf16)
    // buckets (9.6MB) alias B (12.8MB): B dead until gather1 -> gemm1 can
    // run concurrently with bucket_sort (gemm writes A only).
    unsigned*       buckets   = (unsigned*)B;

    const int T256 = 256;
    int gridGemm = (N + 63) / 64;
    int nsort    = (E + SORT_CHUNK - 1) / SORT_CHUNK;
    int gridScl  = (N * 16 + 255) / 256;

    // --- fused CSR-sort || gemm1 (unscaled) ---
    hipMemsetAsync(cursor, 0, (size_t)nfine * 16 * 4, stream);
    sort_gemm1<<<nsort + gridGemm, T256, 0, stream>>>(row, col, buckets, cursor,
                                                      E, nfine, nsort, x, W1, A, N);
    tile_place2<<<nfine, T256, 0, stream>>>(buckets, cursor, rowptr, dinv, srow,
                                            batch, gstart, N, NG, nfine);
    scale_rows<<<gridScl, T256, 0, stream>>>(A, dinv, N);

    // --- conv1 gather (+stats) ---
    gather_conv<<<nblkGa, T256, 0, stream>>>(rowptr, srow, dinv, A, b1, B, psum, psq, N);
    bn_reduce<<<HF, 256, 0, stream>>>(psum, psq, g1, be1, scale, shift, nblkGa, N);

    // --- conv2 (dinv known -> fused rowscale in gemm) ---
    gemm_rt<<<gridGemm, T256, 0, stream>>>(B, W2, A, scale, shift, dinv, N);
    gather_conv<<<nblkGa, T256, 0, stream>>>(rowptr, srow, dinv, A, b2, B, psum, psq, N);
    bn_reduce<<<HF, 256, 0, stream>>>(psum, psq, g2, be2, scale, shift, nblkGa, N);

    // --- fused BN2+ReLU + pooling + classifier ---
    pool_classify<<<NG, 256, 0, stream>>>(B, gstart, scale, shift, Wc, bc, out);
}